// Round 1
// 1275.450 us; speedup vs baseline: 1.5119x; 1.5119x over previous
//
#include <hip/hip_runtime.h>
#include <math.h>

#define QL 1024
#define BSZ 4
#define DM 512
#define NH 8
#define DHH 64
#define MEML 1024
#define KL 2048
#define DMLP 2048

// ---------------- GEMM: C[M,N] = A[M,K] @ W[N,K]^T (+bias, +relu) ----------
template<bool BIAS, bool RELU>
__global__ __launch_bounds__(256)
void gemm_nt(const float* __restrict__ A0, const float* __restrict__ A1, int M0,
             const float* __restrict__ W, const float* __restrict__ bias,
             float* __restrict__ C, int M, int N, int K) {
  __shared__ float As[16][65];
  __shared__ float Bs[16][65];
  const int tid = threadIdx.x;
  const int tx = tid & 15, ty = tid >> 4;
  const int row0 = blockIdx.y * 64, col0 = blockIdx.x * 64;
  float acc[4][4] = {{0.f}};
  const int lr = tid >> 2;
  const int lc = tid & 3;
  const int grow = row0 + lr;
  const float* Arow = (grow < M0) ? (A0 + (size_t)grow * K)
                                  : (A1 + (size_t)(grow - M0) * K);
  const float* Wrow = W + (size_t)(col0 + lr) * K;
  for (int k0 = 0; k0 < K; k0 += 16) {
    float4 a4 = *(const float4*)(Arow + k0 + lc * 4);
    float4 b4 = *(const float4*)(Wrow + k0 + lc * 4);
    As[lc*4+0][lr] = a4.x; As[lc*4+1][lr] = a4.y;
    As[lc*4+2][lr] = a4.z; As[lc*4+3][lr] = a4.w;
    Bs[lc*4+0][lr] = b4.x; Bs[lc*4+1][lr] = b4.y;
    Bs[lc*4+2][lr] = b4.z; Bs[lc*4+3][lr] = b4.w;
    __syncthreads();
    #pragma unroll
    for (int kk = 0; kk < 16; ++kk) {
      float a[4], b[4];
      #pragma unroll
      for (int i2 = 0; i2 < 4; ++i2) a[i2] = As[kk][ty*4+i2];
      #pragma unroll
      for (int j2 = 0; j2 < 4; ++j2) b[j2] = Bs[kk][tx*4+j2];
      #pragma unroll
      for (int i2 = 0; i2 < 4; ++i2)
        #pragma unroll
        for (int j2 = 0; j2 < 4; ++j2)
          acc[i2][j2] += a[i2]*b[j2];
    }
    __syncthreads();
  }
  #pragma unroll
  for (int i2 = 0; i2 < 4; ++i2) {
    const int rr = row0 + ty*4 + i2;
    const int cc = col0 + tx*4;
    float4 o;
    o.x = acc[i2][0]; o.y = acc[i2][1]; o.z = acc[i2][2]; o.w = acc[i2][3];
    if (BIAS) { o.x += bias[cc]; o.y += bias[cc+1]; o.z += bias[cc+2]; o.w += bias[cc+3]; }
    if (RELU) {
      o.x = fmaxf(o.x, 0.f); o.y = fmaxf(o.y, 0.f);
      o.z = fmaxf(o.z, 0.f); o.w = fmaxf(o.w, 0.f);
    }
    *(float4*)(C + (size_t)rr * N + cc) = o;
  }
}

// ---------------- uk[b,h,j] = u_h . k_jbh ; vr[h,jr] = v_h . rk_jr,h --------
__global__ __launch_bounds__(256)
void ukvr_kernel(const float* __restrict__ QKV, const float* __restrict__ RK,
                 const float* __restrict__ u, const float* __restrict__ v,
                 float* __restrict__ UK, float* __restrict__ VR) {
  const int id = blockIdx.x * 256 + threadIdx.x;
  if (id < 65536) {
    const int bh = id >> 11, j = id & 2047;
    const int b = bh >> 3, h = bh & 7;
    const float* kp = QKV + ((size_t)j * 4 + b) * 1536 + 512 + h * 64;
    const float* up = u + h * 64;
    float s = 0.f;
    #pragma unroll
    for (int d = 0; d < 64; ++d) s += up[d] * kp[d];
    UK[id] = s;
  } else if (id < 65536 + 16384) {
    const int e = id - 65536;
    const int h = e >> 11, jr = e & 2047;
    const float* rp = RK + (size_t)jr * 512 + h * 64;
    const float* vp = v + h * 64;
    float s = 0.f;
    #pragma unroll
    for (int d = 0; d < 64; ++d) s += vp[d] * rp[d];
    VR[e] = s;
  }
}

// ---------------- MFMA attention ----------------
typedef __attribute__((ext_vector_type(8))) short bf16x8;
typedef __attribute__((ext_vector_type(4))) float f32x4;

#define MFMA16(A, B, C) __builtin_amdgcn_mfma_f32_16x16x32_bf16((A), (B), (C), 0, 0, 0)
// byte offset into a [64][64] bf16 tile (row stride 128B), T2 XOR-swizzled
#define SWZB(r, cb) (((r) << 7) + ((cb) ^ (((r) & 7) << 4)))
// byte offset into the [64][128] f32 ring (row stride 512B), same swizzle
#define RINGB(r, c) (((r) << 9) + ((((c) << 2)) ^ (((r) & 7) << 4)))
#define CVT2(dst, lo, hi) \
  asm("v_cvt_pk_bf16_f32 %0, %1, %2" : "=v"(dst) : "v"(lo), "v"(hi))

// Block = (64 q-rows, b, h); 4 waves, each wave owns 16 q-rows.
// mfma_f32_16x16x32_bf16 layouts: A lane: m=l&15, k=(l>>4)*8+e;
// B lane: n=l&15, k=(l>>4)*8+e; D lane: n=l&15, m=(l>>4)*4+reg.
__global__ __launch_bounds__(256)
void attn2_kernel(const float* __restrict__ QKV, const float* __restrict__ RK,
                  const float* __restrict__ UK, const float* __restrict__ VR,
                  unsigned short* __restrict__ P, float* __restrict__ INV,
                  float* __restrict__ ATTN) {
  const int b = blockIdx.y;
  const int h = blockIdx.z;
  // pair long+short blocks on the same CU: linear ids c and c+256 share
  // blockIdx.x and differ in h by 4 -> per-CU tile count is constant (49)
  const int i0 = (((h >> 2) & 1) ? (15 - (int)blockIdx.x) : (int)blockIdx.x) * 64;
  const int t = threadIdx.x;
  const int w = t >> 6;          // wave 0..3
  const int lane = t & 63;
  const int lq = lane & 15;
  const int lg = lane >> 4;

  __shared__ __align__(16) unsigned short Ks[4096];  // K tile  [j][d] bf16 swz
  __shared__ __align__(16) unsigned short Rs[4096];  // R tile  [jr][d] bf16 swz
  __shared__ __align__(16) unsigned short Vt[4096];  // V^T tile [d][j] bf16 swz
  __shared__ __align__(16) unsigned short Es[4096];  // P tile  [i][j] bf16 swz (Q stage at prologue)
  __shared__ __align__(16) float Ring[8192];         // BD+vr [i][128] f32 swz
  __shared__ float uks[64];

  // ---- prologue: stage Q (into Es space) + R window jr0p ----
  {
    const int jr0p = 960 - i0;   // in [0,960]
    #pragma unroll
    for (int it = 0; it < 4; ++it) {
      const int idx = it * 256 + t;
      const int row = idx >> 4, c4 = (idx & 15) * 4;
      const float4 q4 = *(const float4*)(QKV + ((size_t)(MEML + i0 + row) * 4 + b) * 1536 + h * 64 + c4);
      uint2 qp; CVT2(qp.x, q4.x, q4.y); CVT2(qp.y, q4.z, q4.w);
      *(uint2*)((char*)Es + SWZB(row, c4 * 2)) = qp;
      const float4 r4 = *(const float4*)(RK + (size_t)(jr0p + row) * 512 + h * 64 + c4);
      uint2 rp; CVT2(rp.x, r4.x, r4.y); CVT2(rp.y, r4.z, r4.w);
      *(uint2*)((char*)Rs + SWZB(row, c4 * 2)) = rp;
    }
  }
  __syncthreads();

  // ---- Q fragments to registers (rows w*16..w*16+15) ----
  const bf16x8 qf0 = *(const bf16x8*)((const char*)Es + SWZB(w * 16 + lq, lg * 16));
  const bf16x8 qf1 = *(const bf16x8*)((const char*)Es + SWZB(w * 16 + lq, 64 + lg * 16));

  // ---- prologue BD -> ring half at cols 64..127 ----
  {
    f32x4 zero = {0.f, 0.f, 0.f, 0.f};
    f32x4 bd[4];
    #pragma unroll
    for (int nj = 0; nj < 4; ++nj) bd[nj] = zero;
    #pragma unroll
    for (int nj = 0; nj < 4; ++nj) {
      const bf16x8 rf0 = *(const bf16x8*)((const char*)Rs + SWZB(nj * 16 + lq, lg * 16));
      const bf16x8 rf1 = *(const bf16x8*)((const char*)Rs + SWZB(nj * 16 + lq, 64 + lg * 16));
      bd[nj] = MFMA16(qf0, rf0, bd[nj]);
      bd[nj] = MFMA16(qf1, rf1, bd[nj]);
    }
    const int jr0p = 960 - i0;
    #pragma unroll
    for (int nj = 0; nj < 4; ++nj) {
      const int jrl = nj * 16 + lq;
      const float vrv = VR[h * 2048 + jr0p + jrl];
      #pragma unroll
      for (int rg = 0; rg < 4; ++rg) {
        const int il = w * 16 + lg * 4 + rg;
        *(float*)((char*)Ring + RINGB(il, 64 + jrl)) = bd[nj][rg] + vrv;
      }
    }
  }

  f32x4 pv[4];
  {
    f32x4 zero = {0.f, 0.f, 0.f, 0.f};
    #pragma unroll
    for (int nd = 0; nd < 4; ++nd) pv[nd] = zero;
  }
  float rs[4] = {0.f, 0.f, 0.f, 0.f};

  const int ntiles = i0 / 64 + 17;
  for (int n = 0; n < ntiles; ++n) {
    const int j0 = n * 64;
    const int jr0 = j0 - i0 + 1024;
    __syncthreads();   // prev iter's Es/Vt/K/R reads done
    // ---- stage K + R (bf16, swizzled) ----
    #pragma unroll
    for (int it = 0; it < 4; ++it) {
      const int idx = it * 256 + t;
      const int row = idx >> 4, c4 = (idx & 15) * 4;
      const float4 k4 = *(const float4*)(QKV + ((size_t)(j0 + row) * 4 + b) * 1536 + 512 + h * 64 + c4);
      uint2 kp; CVT2(kp.x, k4.x, k4.y); CVT2(kp.y, k4.z, k4.w);
      *(uint2*)((char*)Ks + SWZB(row, c4 * 2)) = kp;
      const int jr = jr0 + row;
      float4 r4 = make_float4(0.f, 0.f, 0.f, 0.f);
      if (jr < 2048) r4 = *(const float4*)(RK + (size_t)jr * 512 + h * 64 + c4);
      uint2 rp; CVT2(rp.x, r4.x, r4.y); CVT2(rp.y, r4.z, r4.w);
      *(uint2*)((char*)Rs + SWZB(row, c4 * 2)) = rp;
    }
    // ---- stage V transposed via 4x4 register blocks ----
    {
      const int jb = (t >> 4) * 4, db = (t & 15) * 4;
      const float* vb = QKV + ((size_t)(j0 + jb) * 4 + b) * 1536 + 1024 + h * 64 + db;
      const float4 a0 = *(const float4*)(vb);
      const float4 a1 = *(const float4*)(vb + 6144);
      const float4 a2 = *(const float4*)(vb + 12288);
      const float4 a3 = *(const float4*)(vb + 18432);
      uint2 wv;
      CVT2(wv.x, a0.x, a1.x); CVT2(wv.y, a2.x, a3.x);
      *(uint2*)((char*)Vt + SWZB(db + 0, jb * 2)) = wv;
      CVT2(wv.x, a0.y, a1.y); CVT2(wv.y, a2.y, a3.y);
      *(uint2*)((char*)Vt + SWZB(db + 1, jb * 2)) = wv;
      CVT2(wv.x, a0.z, a1.z); CVT2(wv.y, a2.z, a3.z);
      *(uint2*)((char*)Vt + SWZB(db + 2, jb * 2)) = wv;
      CVT2(wv.x, a0.w, a1.w); CVT2(wv.y, a2.w, a3.w);
      *(uint2*)((char*)Vt + SWZB(db + 3, jb * 2)) = wv;
    }
    if (t < 64) uks[t] = UK[(size_t)(b * 8 + h) * 2048 + j0 + t];
    __syncthreads();
    // ---- AC and BD MFMAs ----
    f32x4 acc[4], bdn[4];
    {
      f32x4 zero = {0.f, 0.f, 0.f, 0.f};
      #pragma unroll
      for (int nj = 0; nj < 4; ++nj) { acc[nj] = zero; bdn[nj] = zero; }
    }
    #pragma unroll
    for (int nj = 0; nj < 4; ++nj) {
      const bf16x8 kf0 = *(const bf16x8*)((const char*)Ks + SWZB(nj * 16 + lq, lg * 16));
      const bf16x8 rf0 = *(const bf16x8*)((const char*)Rs + SWZB(nj * 16 + lq, lg * 16));
      acc[nj] = MFMA16(qf0, kf0, acc[nj]);
      bdn[nj] = MFMA16(qf0, rf0, bdn[nj]);
      const bf16x8 kf1 = *(const bf16x8*)((const char*)Ks + SWZB(nj * 16 + lq, 64 + lg * 16));
      const bf16x8 rf1 = *(const bf16x8*)((const char*)Rs + SWZB(nj * 16 + lq, 64 + lg * 16));
      acc[nj] = MFMA16(qf1, kf1, acc[nj]);
      bdn[nj] = MFMA16(qf1, rf1, bdn[nj]);
    }
    const int base_cur = (n & 1) * 64;
    const int base_prev = 64 - base_cur;
    // ---- ring write (cur half) with vr folded in ----
    #pragma unroll
    for (int nj = 0; nj < 4; ++nj) {
      const int jrl = nj * 16 + lq;
      const int jrg = jr0 + jrl;
      const float vrv = (jrg < 2048) ? VR[h * 2048 + jrg] : 0.f;
      #pragma unroll
      for (int rg = 0; rg < 4; ++rg) {
        const int il = w * 16 + lg * 4 + rg;
        *(float*)((char*)Ring + RINGB(il, base_cur + jrl)) = bdn[nj][rg] + vrv;
      }
    }
    __syncthreads();
    // ---- assemble scores, exp, write P tile (bf16) to Es ----
    #pragma unroll
    for (int njp = 0; njp < 2; ++njp) {
      #pragma unroll
      for (int rg = 0; rg < 4; ++rg) {
        const int il = w * 16 + lg * 4 + rg;
        const int ig = i0 + il;
        float ee[2];
        #pragma unroll
        for (int q2 = 0; q2 < 2; ++q2) {
          const int nj = njp * 2 + q2;
          const int jl = nj * 16 + lq;
          const int jr_rel = jl - il + 63;
          const float ringv = (jr_rel < 64)
              ? *(const float*)((const char*)Ring + RINGB(il, base_prev + jr_rel))
              : *(const float*)((const char*)Ring + RINGB(il, base_cur + jr_rel - 64));
          const float s = 0.125f * (acc[nj][rg] + ringv + uks[jl]);
          const float e = (j0 + jl > ig + MEML) ? 0.f : __expf(s);
          rs[rg] += e;
          ee[q2] = e;
        }
        unsigned int pk2; CVT2(pk2, ee[0], ee[1]);
        const int jlA = (njp * 2) * 16 + lq;
        *(unsigned short*)((char*)Es + SWZB(il, jlA * 2)) = (unsigned short)(pk2 & 0xffffu);
        *(unsigned short*)((char*)Es + SWZB(il, (jlA + 16) * 2)) = (unsigned short)(pk2 >> 16);
      }
    }
    __syncthreads();
    // ---- vectorized P store from Es ----
    #pragma unroll
    for (int it = 0; it < 2; ++it) {
      const int c = it * 256 + t;
      const int row = c >> 3, c16 = c & 7;
      const uint4 val = *(const uint4*)((const char*)Es + SWZB(row, c16 * 16));
      *(uint4*)(P + ((size_t)(b * 8 + h) * 1024 + i0 + row) * 2048 + j0 + c16 * 8) = val;
    }
    // ---- PV MFMAs ----
    {
      const bf16x8 pf0 = *(const bf16x8*)((const char*)Es + SWZB(w * 16 + lq, lg * 16));
      const bf16x8 pf1 = *(const bf16x8*)((const char*)Es + SWZB(w * 16 + lq, 64 + lg * 16));
      #pragma unroll
      for (int nd = 0; nd < 4; ++nd) {
        const bf16x8 vf0 = *(const bf16x8*)((const char*)Vt + SWZB(nd * 16 + lq, lg * 16));
        const bf16x8 vf1 = *(const bf16x8*)((const char*)Vt + SWZB(nd * 16 + lq, 64 + lg * 16));
        pv[nd] = MFMA16(pf0, vf0, pv[nd]);
        pv[nd] = MFMA16(pf1, vf1, pv[nd]);
      }
    }
  }

  // ---- row sums -> inv; write INV; scale PV; store ATTN ----
  #pragma unroll
  for (int rg = 0; rg < 4; ++rg) {
    #pragma unroll
    for (int m = 1; m < 16; m <<= 1) rs[rg] += __shfl_xor(rs[rg], m, 64);
  }
  float inv[4];
  #pragma unroll
  for (int rg = 0; rg < 4; ++rg) inv[rg] = 1.0f / rs[rg];
  if (lq == 0) {
    #pragma unroll
    for (int rg = 0; rg < 4; ++rg)
      INV[(size_t)(b * 8 + h) * 1024 + i0 + w * 16 + lg * 4 + rg] = inv[rg];
  }
  #pragma unroll
  for (int nd = 0; nd < 4; ++nd) {
    #pragma unroll
    for (int rg = 0; rg < 4; ++rg) {
      ATTN[((size_t)(i0 + w * 16 + lg * 4 + rg) * 4 + b) * 512 + h * 64 + nd * 16 + lq] =
          pv[nd][rg] * inv[rg];
    }
  }
}

// ---------------- normalize + transpose P[b,h,i,j](bf16) -> prob[i,j,b,h] --
__global__ __launch_bounds__(256)
void ptrans_kernel(const unsigned short* __restrict__ P, const float* __restrict__ INV,
                   float* __restrict__ prob) {
  const int i  = blockIdx.x;
  const int j0 = blockIdx.y * 64;
  const int t  = threadIdx.x;
  __shared__ float tile[32][65];
  __shared__ float invs[32];
  const bool valid = j0 <= (i & ~63) + MEML;
  if (t < 32) invs[t] = INV[(size_t)t * 1024 + i];
  if (valid) {
    const int bh = t >> 3, part = t & 7;
    const uint4 raw = *(const uint4*)(P + ((size_t)bh * 1024 + i) * 2048 + j0 + part * 8);
    const unsigned int w[4] = {raw.x, raw.y, raw.z, raw.w};
    #pragma unroll
    for (int k = 0; k < 4; ++k) {
      tile[bh][part*8 + 2*k]     = __uint_as_float(w[k] << 16);
      tile[bh][part*8 + 2*k + 1] = __uint_as_float(w[k] & 0xffff0000u);
    }
  }
  __syncthreads();
  #pragma unroll
  for (int it = 0; it < 8; ++it) {
    const int idx = it * 256 + t;
    const int jl = idx >> 5, bh = idx & 31;
    const float val = valid ? tile[bh][jl] * invs[bh] : 0.f;
    prob[((size_t)i * 2048 + j0 + jl) * 32 + bh] = val;
  }
}

// ---------------- Residual + LayerNorm ----------------
__global__ __launch_bounds__(256)
void ln_res_kernel(const float* __restrict__ xa, const float* __restrict__ xb,
                   const float* __restrict__ g, const float* __restrict__ bb,
                   float* __restrict__ y) {
  const int rrow = blockIdx.x;
  const int t = threadIdx.x;
  const size_t base = (size_t)rrow * DM;
  __shared__ float red[256];
  const float a0 = xa[base + t]       + xb[base + t];
  const float a1 = xa[base + t + 256] + xb[base + t + 256];
  red[t] = a0 + a1; __syncthreads();
  for (int s = 128; s > 0; s >>= 1) { if (t < s) red[t] += red[t+s]; __syncthreads(); }
  const float mu = red[0] * (1.0f/512.0f);
  __syncthreads();
  red[t] = a0*a0 + a1*a1; __syncthreads();
  for (int s = 128; s > 0; s >>= 1) { if (t < s) red[t] += red[t+s]; __syncthreads(); }
  const float var = red[0] * (1.0f/512.0f) - mu*mu;
  const float w = rsqrtf(var + 1e-5f);
  y[base + t]       = (a0 - mu) * w * g[t]       + bb[t];
  y[base + t + 256] = (a1 - mu) * w * g[t + 256] + bb[t + 256];
}

extern "C" void kernel_launch(void* const* d_in, const int* in_sizes, int n_in,
                              void* d_out, int out_size, void* d_ws, size_t ws_size,
                              hipStream_t stream) {
  const float* inputs = (const float*)d_in[0];
  const float* r      = (const float*)d_in[1];
  const float* u      = (const float*)d_in[2];
  const float* v      = (const float*)d_in[3];
  const float* mem    = (const float*)d_in[4];
  const float* Wqkv   = (const float*)d_in[6];
  const float* Wr     = (const float*)d_in[7];
  const float* Wo     = (const float*)d_in[8];
  const float* ln1g   = (const float*)d_in[9];
  const float* ln1b   = (const float*)d_in[10];
  const float* w1     = (const float*)d_in[11];
  const float* b1     = (const float*)d_in[12];
  const float* w2     = (const float*)d_in[13];
  const float* b2     = (const float*)d_in[14];
  const float* ln2g   = (const float*)d_in[15];
  const float* ln2b   = (const float*)d_in[16];

  float* out  = (float*)d_out;              // [1024,4,512]
  float* prob = out + (size_t)QL*BSZ*DM;    // [1024,2048,4,8]

  // Workspace (floats). P(bf16) = 33,554,432 float-slots; total ~214 MB.
  float* ws   = (float*)d_ws;
  unsigned short* P = (unsigned short*)ws;   // [4*8][1024][2048] bf16
  float* QKV  = ws + 33554432;               // 8192*1536
  float* RK   = QKV + 12582912;              // 2048*512
  float* ATTN = RK + 1048576;                // 4096*512
  float* AO   = ATTN + 2097152;              // 4096*512
  float* Y    = AO + 2097152;                // 4096*512
  float* UK   = Y + 2097152;                 // 65536
  float* VR   = UK + 65536;                  // 16384
  float* INV  = VR + 16384;                  // 32768
  float* HM   = ws;                          // alias P (dead after ptrans): 4096*2048
  float* Z    = ws + 8388608;                // inside P region

  const dim3 blk256(256);

  gemm_nt<false,false><<<dim3(1536/64, 8192/64), blk256, 0, stream>>>(
      mem, inputs, 4096, Wqkv, nullptr, QKV, 8192, 1536, 512);
  gemm_nt<false,false><<<dim3(512/64, 2048/64), blk256, 0, stream>>>(
      r, r, 2048, Wr, nullptr, RK, 2048, 512, 512);
  ukvr_kernel<<<dim3(320), blk256, 0, stream>>>(QKV, RK, u, v, UK, VR);
  attn2_kernel<<<dim3(16, BSZ, NH), blk256, 0, stream>>>(QKV, RK, UK, VR, P, INV, ATTN);
  ptrans_kernel<<<dim3(1024, 32), blk256, 0, stream>>>(P, INV, prob);
  gemm_nt<false,false><<<dim3(512/64, 4096/64), blk256, 0, stream>>>(
      ATTN, ATTN, 4096, Wo, nullptr, AO, 4096, 512, 512);
  ln_res_kernel<<<dim3(4096), blk256, 0, stream>>>(inputs, AO, ln1g, ln1b, Y);
  gemm_nt<true,true><<<dim3(2048/64, 4096/64), blk256, 0, stream>>>(
      Y, Y, 4096, w1, b1, HM, 4096, 2048, 512);
  gemm_nt<true,false><<<dim3(512/64, 4096/64), blk256, 0, stream>>>(
      HM, HM, 4096, w2, b2, Z, 4096, 512, 2048);
  ln_res_kernel<<<dim3(4096), blk256, 0, stream>>>(Y, Z, ln2g, ln2b, out);
}

// Round 2
// 1049.778 us; speedup vs baseline: 1.8369x; 1.2150x over previous
//
#include <hip/hip_runtime.h>
#include <math.h>

#define QL 1024
#define BSZ 4
#define DM 512
#define NH 8
#define DHH 64
#define MEML 1024
#define KL 2048
#define DMLP 2048

typedef __attribute__((ext_vector_type(8))) short bf16x8;
typedef __attribute__((ext_vector_type(4))) float f32x4;

#define MFMA16(A, B, C) __builtin_amdgcn_mfma_f32_16x16x32_bf16((A), (B), (C), 0, 0, 0)
// byte offset into a [rows][64] bf16 tile (row stride 128B), T2 XOR-swizzled
#define SWZB(r, cb) (((r) << 7) + ((cb) ^ (((r) & 7) << 4)))
// byte offset into the [64][128] f32 ring (row stride 512B), same swizzle
#define RINGB(r, c) (((r) << 9) + ((((c) << 2)) ^ (((r) & 7) << 4)))
#define CVT2(dst, lo, hi) \
  asm("v_cvt_pk_bf16_f32 %0, %1, %2" : "=v"(dst) : "v"(lo), "v"(hi))

// ---------------- MFMA GEMM: C[M,N] = A[M,K] @ W[N,K]^T (+bias, +relu) -----
// Split-bf16: a = hi + lo (both bf16), product a*w ~= ah*wh + ah*wl + al*wh.
// fp32-quality result (residual ~2^-16 rel), 3 MFMAs per logical tile.
// BM in {64,128}; BN = 128 fixed; BK = 64; 256 threads = 4 waves.
template<int BM, bool BIAS, bool RELU>
__global__ __launch_bounds__(256)
void gemm_nt_mfma(const float* __restrict__ A0, const float* __restrict__ A1, int M0,
                  const float* __restrict__ W, const float* __restrict__ bias,
                  float* __restrict__ C, int M, int N, int K) {
  constexpr int MR = 4;                  // 64 rows per wave-tile
  constexpr int NR = (BM == 128) ? 4 : 2;
  __shared__ __align__(16) unsigned short Ahi[BM * 64];
  __shared__ __align__(16) unsigned short Alo[BM * 64];
  __shared__ __align__(16) unsigned short Bhi[128 * 64];
  __shared__ __align__(16) unsigned short Blo[128 * 64];

  const int t = threadIdx.x;
  const int w = t >> 6;
  const int lane = t & 63;
  const int lq = lane & 15;
  const int lg = lane >> 4;
  const int row0 = blockIdx.y * BM, col0 = blockIdx.x * 128;
  const int wrow0 = (BM == 128) ? (w >> 1) * 64 : 0;
  const int wcol0 = (BM == 128) ? (w & 1) * 64 : w * 32;

  f32x4 acc[MR][NR];
  #pragma unroll
  for (int m = 0; m < MR; ++m)
    #pragma unroll
    for (int n = 0; n < NR; ++n)
      acc[m][n] = (f32x4){0.f, 0.f, 0.f, 0.f};

  for (int k0 = 0; k0 < K; k0 += 64) {
    __syncthreads();
    // ---- stage A (fp32 -> hi/lo bf16, swizzled) ----
    #pragma unroll
    for (int it = 0; it < BM / 16; ++it) {
      const int idx = it * 256 + t;
      const int row = idx >> 4, c4 = (idx & 15) * 4;
      const int grow = row0 + row;
      const float* src = (grow < M0) ? (A0 + (size_t)grow * K)
                                     : (A1 + (size_t)(grow - M0) * K);
      const float4 a = *(const float4*)(src + k0 + c4);
      uint2 hi, lo;
      CVT2(hi.x, a.x, a.y); CVT2(hi.y, a.z, a.w);
      float4 res;
      res.x = a.x - __uint_as_float(hi.x << 16);
      res.y = a.y - __uint_as_float(hi.x & 0xffff0000u);
      res.z = a.z - __uint_as_float(hi.y << 16);
      res.w = a.w - __uint_as_float(hi.y & 0xffff0000u);
      CVT2(lo.x, res.x, res.y); CVT2(lo.y, res.z, res.w);
      *(uint2*)((char*)Ahi + SWZB(row, c4 * 2)) = hi;
      *(uint2*)((char*)Alo + SWZB(row, c4 * 2)) = lo;
    }
    // ---- stage W ----
    #pragma unroll
    for (int it = 0; it < 8; ++it) {
      const int idx = it * 256 + t;
      const int row = idx >> 4, c4 = (idx & 15) * 4;
      const float4 a = *(const float4*)(W + (size_t)(col0 + row) * K + k0 + c4);
      uint2 hi, lo;
      CVT2(hi.x, a.x, a.y); CVT2(hi.y, a.z, a.w);
      float4 res;
      res.x = a.x - __uint_as_float(hi.x << 16);
      res.y = a.y - __uint_as_float(hi.x & 0xffff0000u);
      res.z = a.z - __uint_as_float(hi.y << 16);
      res.w = a.w - __uint_as_float(hi.y & 0xffff0000u);
      CVT2(lo.x, res.x, res.y); CVT2(lo.y, res.z, res.w);
      *(uint2*)((char*)Bhi + SWZB(row, c4 * 2)) = hi;
      *(uint2*)((char*)Blo + SWZB(row, c4 * 2)) = lo;
    }
    __syncthreads();
    // ---- MFMA compute ----
    #pragma unroll
    for (int ks = 0; ks < 2; ++ks) {
      bf16x8 ah[MR], al[MR], bh[NR], bl[NR];
      #pragma unroll
      for (int m = 0; m < MR; ++m) {
        ah[m] = *(const bf16x8*)((const char*)Ahi + SWZB(wrow0 + m * 16 + lq, ks * 64 + lg * 16));
        al[m] = *(const bf16x8*)((const char*)Alo + SWZB(wrow0 + m * 16 + lq, ks * 64 + lg * 16));
      }
      #pragma unroll
      for (int n = 0; n < NR; ++n) {
        bh[n] = *(const bf16x8*)((const char*)Bhi + SWZB(wcol0 + n * 16 + lq, ks * 64 + lg * 16));
        bl[n] = *(const bf16x8*)((const char*)Blo + SWZB(wcol0 + n * 16 + lq, ks * 64 + lg * 16));
      }
      #pragma unroll
      for (int m = 0; m < MR; ++m)
        #pragma unroll
        for (int n = 0; n < NR; ++n) {
          acc[m][n] = MFMA16(ah[m], bh[n], acc[m][n]);
          acc[m][n] = MFMA16(ah[m], bl[n], acc[m][n]);
          acc[m][n] = MFMA16(al[m], bh[n], acc[m][n]);
        }
    }
  }
  // ---- epilogue ----
  #pragma unroll
  for (int n = 0; n < NR; ++n) {
    const int col = col0 + wcol0 + n * 16 + lq;
    const float bv = BIAS ? bias[col] : 0.f;
    #pragma unroll
    for (int m = 0; m < MR; ++m) {
      #pragma unroll
      for (int rg = 0; rg < 4; ++rg) {
        const int row = row0 + wrow0 + m * 16 + lg * 4 + rg;
        float vv = acc[m][n][rg] + bv;
        if (RELU) vv = fmaxf(vv, 0.f);
        C[(size_t)row * N + col] = vv;
      }
    }
  }
}

// ---------------- uk[b,h,j] = u_h . k_jbh ; vr[h,jr] = v_h . rk_jr,h --------
__global__ __launch_bounds__(256)
void ukvr_kernel(const float* __restrict__ QKV, const float* __restrict__ RK,
                 const float* __restrict__ u, const float* __restrict__ v,
                 float* __restrict__ UK, float* __restrict__ VR) {
  const int id = blockIdx.x * 256 + threadIdx.x;
  if (id < 65536) {
    const int bh = id >> 11, j = id & 2047;
    const int b = bh >> 3, h = bh & 7;
    const float* kp = QKV + ((size_t)j * 4 + b) * 1536 + 512 + h * 64;
    const float* up = u + h * 64;
    float s = 0.f;
    #pragma unroll
    for (int d = 0; d < 64; ++d) s += up[d] * kp[d];
    UK[id] = s;
  } else if (id < 65536 + 16384) {
    const int e = id - 65536;
    const int h = e >> 11, jr = e & 2047;
    const float* rp = RK + (size_t)jr * 512 + h * 64;
    const float* vp = v + h * 64;
    float s = 0.f;
    #pragma unroll
    for (int d = 0; d < 64; ++d) s += vp[d] * rp[d];
    VR[e] = s;
  }
}

// ---------------- MFMA attention ----------------
// Block = (64 q-rows, b, h); 4 waves, each wave owns 16 q-rows.
__global__ __launch_bounds__(256)
void attn2_kernel(const float* __restrict__ QKV, const float* __restrict__ RK,
                  const float* __restrict__ UK, const float* __restrict__ VR,
                  unsigned short* __restrict__ P, float* __restrict__ INV,
                  float* __restrict__ ATTN) {
  const int b = blockIdx.y;
  const int h = blockIdx.z;
  const int i0 = (((h >> 2) & 1) ? (15 - (int)blockIdx.x) : (int)blockIdx.x) * 64;
  const int t = threadIdx.x;
  const int w = t >> 6;          // wave 0..3
  const int lane = t & 63;
  const int lq = lane & 15;
  const int lg = lane >> 4;

  __shared__ __align__(16) unsigned short Ks[4096];  // K tile  [j][d] bf16 swz
  __shared__ __align__(16) unsigned short Rs[4096];  // R tile  [jr][d] bf16 swz
  __shared__ __align__(16) unsigned short Vt[4096];  // V^T tile [d][j] bf16 swz
  __shared__ __align__(16) unsigned short Es[4096];  // P tile  [i][j] bf16 swz (Q stage at prologue)
  __shared__ __align__(16) float Ring[8192];         // BD+vr [i][128] f32 swz
  __shared__ float uks[64];

  // ---- prologue: stage Q (into Es space) + R window jr0p ----
  {
    const int jr0p = 960 - i0;   // in [0,960]
    #pragma unroll
    for (int it = 0; it < 4; ++it) {
      const int idx = it * 256 + t;
      const int row = idx >> 4, c4 = (idx & 15) * 4;
      const float4 q4 = *(const float4*)(QKV + ((size_t)(MEML + i0 + row) * 4 + b) * 1536 + h * 64 + c4);
      uint2 qp; CVT2(qp.x, q4.x, q4.y); CVT2(qp.y, q4.z, q4.w);
      *(uint2*)((char*)Es + SWZB(row, c4 * 2)) = qp;
      const float4 r4 = *(const float4*)(RK + (size_t)(jr0p + row) * 512 + h * 64 + c4);
      uint2 rp; CVT2(rp.x, r4.x, r4.y); CVT2(rp.y, r4.z, r4.w);
      *(uint2*)((char*)Rs + SWZB(row, c4 * 2)) = rp;
    }
  }
  __syncthreads();

  // ---- Q fragments to registers (rows w*16..w*16+15) ----
  const bf16x8 qf0 = *(const bf16x8*)((const char*)Es + SWZB(w * 16 + lq, lg * 16));
  const bf16x8 qf1 = *(const bf16x8*)((const char*)Es + SWZB(w * 16 + lq, 64 + lg * 16));

  // ---- prologue BD -> ring half at cols 64..127 ----
  {
    f32x4 zero = {0.f, 0.f, 0.f, 0.f};
    f32x4 bd[4];
    #pragma unroll
    for (int nj = 0; nj < 4; ++nj) bd[nj] = zero;
    #pragma unroll
    for (int nj = 0; nj < 4; ++nj) {
      const bf16x8 rf0 = *(const bf16x8*)((const char*)Rs + SWZB(nj * 16 + lq, lg * 16));
      const bf16x8 rf1 = *(const bf16x8*)((const char*)Rs + SWZB(nj * 16 + lq, 64 + lg * 16));
      bd[nj] = MFMA16(qf0, rf0, bd[nj]);
      bd[nj] = MFMA16(qf1, rf1, bd[nj]);
    }
    const int jr0p = 960 - i0;
    #pragma unroll
    for (int nj = 0; nj < 4; ++nj) {
      const int jrl = nj * 16 + lq;
      const float vrv = VR[h * 2048 + jr0p + jrl];
      #pragma unroll
      for (int rg = 0; rg < 4; ++rg) {
        const int il = w * 16 + lg * 4 + rg;
        *(float*)((char*)Ring + RINGB(il, 64 + jrl)) = bd[nj][rg] + vrv;
      }
    }
  }

  f32x4 pv[4];
  {
    f32x4 zero = {0.f, 0.f, 0.f, 0.f};
    #pragma unroll
    for (int nd = 0; nd < 4; ++nd) pv[nd] = zero;
  }
  float rs[4] = {0.f, 0.f, 0.f, 0.f};

  const int ntiles = i0 / 64 + 17;
  for (int n = 0; n < ntiles; ++n) {
    const int j0 = n * 64;
    const int jr0 = j0 - i0 + 1024;
    __syncthreads();   // prev iter's Es/Vt/K/R reads done
    // ---- stage K + R (bf16, swizzled) ----
    #pragma unroll
    for (int it = 0; it < 4; ++it) {
      const int idx = it * 256 + t;
      const int row = idx >> 4, c4 = (idx & 15) * 4;
      const float4 k4 = *(const float4*)(QKV + ((size_t)(j0 + row) * 4 + b) * 1536 + 512 + h * 64 + c4);
      uint2 kp; CVT2(kp.x, k4.x, k4.y); CVT2(kp.y, k4.z, k4.w);
      *(uint2*)((char*)Ks + SWZB(row, c4 * 2)) = kp;
      const int jr = jr0 + row;
      float4 r4 = make_float4(0.f, 0.f, 0.f, 0.f);
      if (jr < 2048) r4 = *(const float4*)(RK + (size_t)jr * 512 + h * 64 + c4);
      uint2 rp; CVT2(rp.x, r4.x, r4.y); CVT2(rp.y, r4.z, r4.w);
      *(uint2*)((char*)Rs + SWZB(row, c4 * 2)) = rp;
    }
    // ---- stage V transposed via 4x4 register blocks ----
    {
      const int jb = (t >> 4) * 4, db = (t & 15) * 4;
      const float* vb = QKV + ((size_t)(j0 + jb) * 4 + b) * 1536 + 1024 + h * 64 + db;
      const float4 a0 = *(const float4*)(vb);
      const float4 a1 = *(const float4*)(vb + 6144);
      const float4 a2 = *(const float4*)(vb + 12288);
      const float4 a3 = *(const float4*)(vb + 18432);
      uint2 wv;
      CVT2(wv.x, a0.x, a1.x); CVT2(wv.y, a2.x, a3.x);
      *(uint2*)((char*)Vt + SWZB(db + 0, jb * 2)) = wv;
      CVT2(wv.x, a0.y, a1.y); CVT2(wv.y, a2.y, a3.y);
      *(uint2*)((char*)Vt + SWZB(db + 1, jb * 2)) = wv;
      CVT2(wv.x, a0.z, a1.z); CVT2(wv.y, a2.z, a3.z);
      *(uint2*)((char*)Vt + SWZB(db + 2, jb * 2)) = wv;
      CVT2(wv.x, a0.w, a1.w); CVT2(wv.y, a2.w, a3.w);
      *(uint2*)((char*)Vt + SWZB(db + 3, jb * 2)) = wv;
    }
    if (t < 64) uks[t] = UK[(size_t)(b * 8 + h) * 2048 + j0 + t];
    __syncthreads();
    // ---- AC and BD MFMAs ----
    f32x4 acc[4], bdn[4];
    {
      f32x4 zero = {0.f, 0.f, 0.f, 0.f};
      #pragma unroll
      for (int nj = 0; nj < 4; ++nj) { acc[nj] = zero; bdn[nj] = zero; }
    }
    #pragma unroll
    for (int nj = 0; nj < 4; ++nj) {
      const bf16x8 kf0 = *(const bf16x8*)((const char*)Ks + SWZB(nj * 16 + lq, lg * 16));
      const bf16x8 rf0 = *(const bf16x8*)((const char*)Rs + SWZB(nj * 16 + lq, lg * 16));
      acc[nj] = MFMA16(qf0, kf0, acc[nj]);
      bdn[nj] = MFMA16(qf0, rf0, bdn[nj]);
      const bf16x8 kf1 = *(const bf16x8*)((const char*)Ks + SWZB(nj * 16 + lq, 64 + lg * 16));
      const bf16x8 rf1 = *(const bf16x8*)((const char*)Rs + SWZB(nj * 16 + lq, 64 + lg * 16));
      acc[nj] = MFMA16(qf1, kf1, acc[nj]);
      bdn[nj] = MFMA16(qf1, rf1, bdn[nj]);
    }
    const int base_cur = (n & 1) * 64;
    const int base_prev = 64 - base_cur;
    // ---- ring write (cur half) with vr folded in ----
    #pragma unroll
    for (int nj = 0; nj < 4; ++nj) {
      const int jrl = nj * 16 + lq;
      const int jrg = jr0 + jrl;
      const float vrv = (jrg < 2048) ? VR[h * 2048 + jrg] : 0.f;
      #pragma unroll
      for (int rg = 0; rg < 4; ++rg) {
        const int il = w * 16 + lg * 4 + rg;
        *(float*)((char*)Ring + RINGB(il, base_cur + jrl)) = bdn[nj][rg] + vrv;
      }
    }
    __syncthreads();
    // ---- assemble scores, exp, write P tile (bf16) to Es ----
    #pragma unroll
    for (int njp = 0; njp < 2; ++njp) {
      #pragma unroll
      for (int rg = 0; rg < 4; ++rg) {
        const int il = w * 16 + lg * 4 + rg;
        const int ig = i0 + il;
        float ee[2];
        #pragma unroll
        for (int q2 = 0; q2 < 2; ++q2) {
          const int nj = njp * 2 + q2;
          const int jl = nj * 16 + lq;
          const int jr_rel = jl - il + 63;
          const float ringv = (jr_rel < 64)
              ? *(const float*)((const char*)Ring + RINGB(il, base_prev + jr_rel))
              : *(const float*)((const char*)Ring + RINGB(il, base_cur + jr_rel - 64));
          const float s = 0.125f * (acc[nj][rg] + ringv + uks[jl]);
          const float e = (j0 + jl > ig + MEML) ? 0.f : __expf(s);
          rs[rg] += e;
          ee[q2] = e;
        }
        unsigned int pk2; CVT2(pk2, ee[0], ee[1]);
        const int jlA = (njp * 2) * 16 + lq;
        *(unsigned short*)((char*)Es + SWZB(il, jlA * 2)) = (unsigned short)(pk2 & 0xffffu);
        *(unsigned short*)((char*)Es + SWZB(il, (jlA + 16) * 2)) = (unsigned short)(pk2 >> 16);
      }
    }
    __syncthreads();
    // ---- vectorized P store from Es ----
    #pragma unroll
    for (int it = 0; it < 2; ++it) {
      const int c = it * 256 + t;
      const int row = c >> 3, c16 = c & 7;
      const uint4 val = *(const uint4*)((const char*)Es + SWZB(row, c16 * 16));
      *(uint4*)(P + ((size_t)(b * 8 + h) * 1024 + i0 + row) * 2048 + j0 + c16 * 8) = val;
    }
    // ---- PV MFMAs ----
    {
      const bf16x8 pf0 = *(const bf16x8*)((const char*)Es + SWZB(w * 16 + lq, lg * 16));
      const bf16x8 pf1 = *(const bf16x8*)((const char*)Es + SWZB(w * 16 + lq, 64 + lg * 16));
      #pragma unroll
      for (int nd = 0; nd < 4; ++nd) {
        const bf16x8 vf0 = *(const bf16x8*)((const char*)Vt + SWZB(nd * 16 + lq, lg * 16));
        const bf16x8 vf1 = *(const bf16x8*)((const char*)Vt + SWZB(nd * 16 + lq, 64 + lg * 16));
        pv[nd] = MFMA16(pf0, vf0, pv[nd]);
        pv[nd] = MFMA16(pf1, vf1, pv[nd]);
      }
    }
  }

  // ---- row sums -> inv; write INV; scale PV; store ATTN ----
  #pragma unroll
  for (int rg = 0; rg < 4; ++rg) {
    #pragma unroll
    for (int m = 1; m < 16; m <<= 1) rs[rg] += __shfl_xor(rs[rg], m, 64);
  }
  float inv[4];
  #pragma unroll
  for (int rg = 0; rg < 4; ++rg) inv[rg] = 1.0f / rs[rg];
  if (lq == 0) {
    #pragma unroll
    for (int rg = 0; rg < 4; ++rg)
      INV[(size_t)(b * 8 + h) * 1024 + i0 + w * 16 + lg * 4 + rg] = inv[rg];
  }
  #pragma unroll
  for (int nd = 0; nd < 4; ++nd) {
    #pragma unroll
    for (int rg = 0; rg < 4; ++rg) {
      ATTN[((size_t)(i0 + w * 16 + lg * 4 + rg) * 4 + b) * 512 + h * 64 + nd * 16 + lq] =
          pv[nd][rg] * inv[rg];
    }
  }
}

// ---------------- normalize + transpose P[b,h,i,j](bf16) -> prob[i,j,b,h] --
__global__ __launch_bounds__(256)
void ptrans_kernel(const unsigned short* __restrict__ P, const float* __restrict__ INV,
                   float* __restrict__ prob) {
  const int i  = blockIdx.x;
  const int j0 = blockIdx.y * 64;
  const int t  = threadIdx.x;
  __shared__ float tile[32][65];
  __shared__ float invs[32];
  const bool valid = j0 <= (i & ~63) + MEML;
  if (t < 32) invs[t] = INV[(size_t)t * 1024 + i];
  if (valid) {
    const int bh = t >> 3, part = t & 7;
    const uint4 raw = *(const uint4*)(P + ((size_t)bh * 1024 + i) * 2048 + j0 + part * 8);
    const unsigned int w[4] = {raw.x, raw.y, raw.z, raw.w};
    #pragma unroll
    for (int k = 0; k < 4; ++k) {
      tile[bh][part*8 + 2*k]     = __uint_as_float(w[k] << 16);
      tile[bh][part*8 + 2*k + 1] = __uint_as_float(w[k] & 0xffff0000u);
    }
  }
  __syncthreads();
  #pragma unroll
  for (int it = 0; it < 8; ++it) {
    const int idx = it * 256 + t;
    const int jl = idx >> 5, bh = idx & 31;
    const float val = valid ? tile[bh][jl] * invs[bh] : 0.f;
    prob[((size_t)i * 2048 + j0 + jl) * 32 + bh] = val;
  }
}

// ---------------- Residual + LayerNorm ----------------
__global__ __launch_bounds__(256)
void ln_res_kernel(const float* __restrict__ xa, const float* __restrict__ xb,
                   const float* __restrict__ g, const float* __restrict__ bb,
                   float* __restrict__ y) {
  const int rrow = blockIdx.x;
  const int t = threadIdx.x;
  const size_t base = (size_t)rrow * DM;
  __shared__ float red[256];
  const float a0 = xa[base + t]       + xb[base + t];
  const float a1 = xa[base + t + 256] + xb[base + t + 256];
  red[t] = a0 + a1; __syncthreads();
  for (int s = 128; s > 0; s >>= 1) { if (t < s) red[t] += red[t+s]; __syncthreads(); }
  const float mu = red[0] * (1.0f/512.0f);
  __syncthreads();
  red[t] = a0*a0 + a1*a1; __syncthreads();
  for (int s = 128; s > 0; s >>= 1) { if (t < s) red[t] += red[t+s]; __syncthreads(); }
  const float var = red[0] * (1.0f/512.0f) - mu*mu;
  const float w = rsqrtf(var + 1e-5f);
  y[base + t]       = (a0 - mu) * w * g[t]       + bb[t];
  y[base + t + 256] = (a1 - mu) * w * g[t + 256] + bb[t + 256];
}

extern "C" void kernel_launch(void* const* d_in, const int* in_sizes, int n_in,
                              void* d_out, int out_size, void* d_ws, size_t ws_size,
                              hipStream_t stream) {
  const float* inputs = (const float*)d_in[0];
  const float* r      = (const float*)d_in[1];
  const float* u      = (const float*)d_in[2];
  const float* v      = (const float*)d_in[3];
  const float* mem    = (const float*)d_in[4];
  const float* Wqkv   = (const float*)d_in[6];
  const float* Wr     = (const float*)d_in[7];
  const float* Wo     = (const float*)d_in[8];
  const float* ln1g   = (const float*)d_in[9];
  const float* ln1b   = (const float*)d_in[10];
  const float* w1     = (const float*)d_in[11];
  const float* b1     = (const float*)d_in[12];
  const float* w2     = (const float*)d_in[13];
  const float* b2     = (const float*)d_in[14];
  const float* ln2g   = (const float*)d_in[15];
  const float* ln2b   = (const float*)d_in[16];

  float* out  = (float*)d_out;              // [1024,4,512]
  float* prob = out + (size_t)QL*BSZ*DM;    // [1024,2048,4,8]

  // Workspace (floats). P(bf16) = 33,554,432 float-slots; total ~214 MB.
  float* ws   = (float*)d_ws;
  unsigned short* P = (unsigned short*)ws;   // [4*8][1024][2048] bf16
  float* QKV  = ws + 33554432;               // 8192*1536
  float* RK   = QKV + 12582912;              // 2048*512
  float* ATTN = RK + 1048576;                // 4096*512
  float* AO   = ATTN + 2097152;              // 4096*512
  float* Y    = AO + 2097152;                // 4096*512
  float* UK   = Y + 2097152;                 // 65536
  float* VR   = UK + 65536;                  // 16384
  float* INV  = VR + 16384;                  // 32768
  float* HM   = ws;                          // alias P (dead after ptrans): 4096*2048
  float* Z    = ws + 8388608;                // inside P region

  const dim3 blk256(256);

  // QKV: [8192,1536] = cat(mem,inputs) @ Wqkv^T, K=512
  gemm_nt_mfma<128,false,false><<<dim3(1536/128, 8192/128), blk256, 0, stream>>>(
      mem, inputs, 4096, Wqkv, nullptr, QKV, 8192, 1536, 512);
  // RK: [2048,512] = r @ Wr^T, K=512
  gemm_nt_mfma<64,false,false><<<dim3(512/128, 2048/64), blk256, 0, stream>>>(
      r, r, 2048, Wr, nullptr, RK, 2048, 512, 512);
  ukvr_kernel<<<dim3(320), blk256, 0, stream>>>(QKV, RK, u, v, UK, VR);
  attn2_kernel<<<dim3(16, BSZ, NH), blk256, 0, stream>>>(QKV, RK, UK, VR, P, INV, ATTN);
  ptrans_kernel<<<dim3(1024, 32), blk256, 0, stream>>>(P, INV, prob);
  // AO: [4096,512] = ATTN @ Wo^T, K=512
  gemm_nt_mfma<64,false,false><<<dim3(512/128, 4096/64), blk256, 0, stream>>>(
      ATTN, ATTN, 4096, Wo, nullptr, AO, 4096, 512, 512);
  ln_res_kernel<<<dim3(4096), blk256, 0, stream>>>(inputs, AO, ln1g, ln1b, Y);
  // HM: [4096,2048] = Y @ w1^T + b1, relu, K=512
  gemm_nt_mfma<128,true,true><<<dim3(2048/128, 4096/128), blk256, 0, stream>>>(
      Y, Y, 4096, w1, b1, HM, 4096, 2048, 512);
  // Z: [4096,512] = HM @ w2^T + b2, K=2048
  gemm_nt_mfma<64,true,false><<<dim3(512/128, 4096/64), blk256, 0, stream>>>(
      HM, HM, 4096, w2, b2, Z, 4096, 512, 2048);
  ln_res_kernel<<<dim3(4096), blk256, 0, stream>>>(Y, Z, ln2g, ln2b, out);
}

// Round 3
// 721.727 us; speedup vs baseline: 2.6719x; 1.4545x over previous
//
#include <hip/hip_runtime.h>
#include <math.h>

#define QL 1024
#define BSZ 4
#define DM 512
#define NH 8
#define DHH 64
#define MEML 1024
#define KL 2048
#define DMLP 2048

typedef __attribute__((ext_vector_type(8))) short bf16x8;
typedef __attribute__((ext_vector_type(4))) float f32x4;

#define MFMA16(A, B, C) __builtin_amdgcn_mfma_f32_16x16x32_bf16((A), (B), (C), 0, 0, 0)
// byte offset into a [rows][64] bf16 tile (row stride 128B), T2 XOR-swizzled
#define SWZB(r, cb) (((r) << 7) + ((cb) ^ (((r) & 7) << 4)))
// byte offset into the [64][128] f32 ring (row stride 512B), same swizzle
#define RINGB(r, c) (((r) << 9) + ((((c) << 2)) ^ (((r) & 7) << 4)))
#define CVT2(dst, lo, hi) \
  asm("v_cvt_pk_bf16_f32 %0, %1, %2" : "=v"(dst) : "v"(lo), "v"(hi))

// ---------------- precvt: fp32 -> (hi, lo) bf16 split arrays ---------------
__global__ __launch_bounds__(256)
void precvt_kernel(const float* __restrict__ src, unsigned short* __restrict__ hi,
                   unsigned short* __restrict__ lo, int n4) {
  const int i = blockIdx.x * 256 + threadIdx.x;
  if (i >= n4) return;
  const float4 a = ((const float4*)src)[i];
  uint2 h, l;
  CVT2(h.x, a.x, a.y); CVT2(h.y, a.z, a.w);
  float4 res;
  res.x = a.x - __uint_as_float(h.x << 16);
  res.y = a.y - __uint_as_float(h.x & 0xffff0000u);
  res.z = a.z - __uint_as_float(h.y << 16);
  res.w = a.w - __uint_as_float(h.y & 0xffff0000u);
  CVT2(l.x, res.x, res.y); CVT2(l.y, res.z, res.w);
  ((uint2*)hi)[i] = h;
  ((uint2*)lo)[i] = l;
}

// ---------------- MFMA GEMM: C[M,N] = A[M,K] @ W[N,K]^T (+bias, +relu) -----
// Split-bf16: a = hi + lo, a*w ~= ah*wh + ah*wl + al*wh (fp32-quality).
// W always from precvt hi/lo arrays. A either precvt (APRE) or in-loop cvt.
// Prefetch: next K-tile's global loads issued after the post-stage barrier;
// consumed at next loop-top barrier (whose vmcnt(0) drain is the wait).
template<int BM, bool APRE, bool BIAS, bool RELU>
__global__ __launch_bounds__(256)
void gemm_nt_mfma(const float* __restrict__ A0, const float* __restrict__ A1, int M0,
                  const unsigned short* __restrict__ AhiG, const unsigned short* __restrict__ AloG,
                  const unsigned short* __restrict__ WhiG, const unsigned short* __restrict__ WloG,
                  const float* __restrict__ bias,
                  float* __restrict__ C, int M, int N, int K) {
  constexpr int MR = 4;
  constexpr int NR = (BM == 128) ? 4 : 2;
  constexpr int AU = BM / 16;
  __shared__ __align__(16) unsigned short Ahi[BM * 64];
  __shared__ __align__(16) unsigned short Alo[BM * 64];
  __shared__ __align__(16) unsigned short Bhi[128 * 64];
  __shared__ __align__(16) unsigned short Blo[128 * 64];

  const int t = threadIdx.x;
  const int w = t >> 6;
  const int lane = t & 63;
  const int lq = lane & 15;
  const int lg = lane >> 4;
  const int row0 = blockIdx.y * BM, col0 = blockIdx.x * 128;
  const int wrow0 = (BM == 128) ? (w >> 1) * 64 : 0;
  const int wcol0 = (BM == 128) ? (w & 1) * 64 : w * 32;

  float4 paf[AU];
  uint2 pah[AU], pal[AU];
  uint2 pwh[8], pwl[8];

  auto loadAB = [&](int k0) {
    #pragma unroll
    for (int it = 0; it < AU; ++it) {
      const int idx = it * 256 + t;
      const int row = idx >> 4, c4 = (idx & 15) * 4;
      if (APRE) {
        const size_t off = (size_t)(row0 + row) * K + k0 + c4;
        pah[it] = *(const uint2*)(AhiG + off);
        pal[it] = *(const uint2*)(AloG + off);
      } else {
        const int grow = row0 + row;
        const float* src = (grow < M0) ? (A0 + (size_t)grow * K)
                                       : (A1 + (size_t)(grow - M0) * K);
        paf[it] = *(const float4*)(src + k0 + c4);
      }
    }
    #pragma unroll
    for (int it = 0; it < 8; ++it) {
      const int idx = it * 256 + t;
      const int row = idx >> 4, c4 = (idx & 15) * 4;
      const size_t off = (size_t)(col0 + row) * K + k0 + c4;
      pwh[it] = *(const uint2*)(WhiG + off);
      pwl[it] = *(const uint2*)(WloG + off);
    }
  };

  f32x4 acc[MR][NR];
  #pragma unroll
  for (int m = 0; m < MR; ++m)
    #pragma unroll
    for (int n = 0; n < NR; ++n)
      acc[m][n] = (f32x4){0.f, 0.f, 0.f, 0.f};

  loadAB(0);
  for (int k0 = 0; k0 < K; k0 += 64) {
    __syncthreads();   // drains prefetch loads; prev MFMA done with LDS
    #pragma unroll
    for (int it = 0; it < AU; ++it) {
      const int idx = it * 256 + t;
      const int row = idx >> 4, cb = (idx & 15) * 8;
      uint2 hi, lo;
      if (APRE) {
        hi = pah[it]; lo = pal[it];
      } else {
        const float4 a = paf[it];
        CVT2(hi.x, a.x, a.y); CVT2(hi.y, a.z, a.w);
        float4 res;
        res.x = a.x - __uint_as_float(hi.x << 16);
        res.y = a.y - __uint_as_float(hi.x & 0xffff0000u);
        res.z = a.z - __uint_as_float(hi.y << 16);
        res.w = a.w - __uint_as_float(hi.y & 0xffff0000u);
        CVT2(lo.x, res.x, res.y); CVT2(lo.y, res.z, res.w);
      }
      *(uint2*)((char*)Ahi + SWZB(row, cb)) = hi;
      *(uint2*)((char*)Alo + SWZB(row, cb)) = lo;
    }
    #pragma unroll
    for (int it = 0; it < 8; ++it) {
      const int idx = it * 256 + t;
      const int row = idx >> 4, cb = (idx & 15) * 8;
      *(uint2*)((char*)Bhi + SWZB(row, cb)) = pwh[it];
      *(uint2*)((char*)Blo + SWZB(row, cb)) = pwl[it];
    }
    __syncthreads();   // LDS tiles visible
    if (k0 + 64 < K) loadAB(k0 + 64);   // prefetch in flight during MFMA
    #pragma unroll
    for (int ks = 0; ks < 2; ++ks) {
      bf16x8 ah[MR], al[MR], bh[NR], bl[NR];
      #pragma unroll
      for (int m = 0; m < MR; ++m) {
        ah[m] = *(const bf16x8*)((const char*)Ahi + SWZB(wrow0 + m * 16 + lq, ks * 64 + lg * 16));
        al[m] = *(const bf16x8*)((const char*)Alo + SWZB(wrow0 + m * 16 + lq, ks * 64 + lg * 16));
      }
      #pragma unroll
      for (int n = 0; n < NR; ++n) {
        bh[n] = *(const bf16x8*)((const char*)Bhi + SWZB(wcol0 + n * 16 + lq, ks * 64 + lg * 16));
        bl[n] = *(const bf16x8*)((const char*)Blo + SWZB(wcol0 + n * 16 + lq, ks * 64 + lg * 16));
      }
      #pragma unroll
      for (int m = 0; m < MR; ++m)
        #pragma unroll
        for (int n = 0; n < NR; ++n) {
          acc[m][n] = MFMA16(ah[m], bh[n], acc[m][n]);
          acc[m][n] = MFMA16(ah[m], bl[n], acc[m][n]);
          acc[m][n] = MFMA16(al[m], bh[n], acc[m][n]);
        }
    }
  }
  // ---- epilogue ----
  #pragma unroll
  for (int n = 0; n < NR; ++n) {
    const int col = col0 + wcol0 + n * 16 + lq;
    const float bv = BIAS ? bias[col] : 0.f;
    #pragma unroll
    for (int m = 0; m < MR; ++m) {
      #pragma unroll
      for (int rg = 0; rg < 4; ++rg) {
        const int row = row0 + wrow0 + m * 16 + lg * 4 + rg;
        float vv = acc[m][n][rg] + bv;
        if (RELU) vv = fmaxf(vv, 0.f);
        C[(size_t)row * N + col] = vv;
      }
    }
  }
}

// ---------------- uk[b,h,j] = u_h . k_jbh ; vr[h,jr] = v_h . rk_jr,h --------
__global__ __launch_bounds__(256)
void ukvr_kernel(const float* __restrict__ QKV, const float* __restrict__ RK,
                 const float* __restrict__ u, const float* __restrict__ v,
                 float* __restrict__ UK, float* __restrict__ VR) {
  const int id = blockIdx.x * 256 + threadIdx.x;
  if (id < 65536) {
    const int bh = id >> 11, j = id & 2047;
    const int b = bh >> 3, h = bh & 7;
    const float* kp = QKV + ((size_t)j * 4 + b) * 1536 + 512 + h * 64;
    const float* up = u + h * 64;
    float s = 0.f;
    #pragma unroll
    for (int d = 0; d < 64; ++d) s += up[d] * kp[d];
    UK[id] = s;
  } else if (id < 65536 + 16384) {
    const int e = id - 65536;
    const int h = e >> 11, jr = e & 2047;
    const float* rp = RK + (size_t)jr * 512 + h * 64;
    const float* vp = v + h * 64;
    float s = 0.f;
    #pragma unroll
    for (int d = 0; d < 64; ++d) s += vp[d] * rp[d];
    VR[e] = s;
  }
}

// ---------------- MFMA attention ----------------
// Block = (64 q-rows, b, h); 4 waves, each wave owns 16 q-rows.
// 3 barriers/tile; Ring and Es are intra-wave (rows owned by the writing
// wave) so no barrier between ring-write/exp and Es-write/PV.
__global__ __launch_bounds__(256)
void attn2_kernel(const float* __restrict__ QKV, const float* __restrict__ RK,
                  const float* __restrict__ UK, const float* __restrict__ VR,
                  unsigned short* __restrict__ P, float* __restrict__ INV,
                  float* __restrict__ ATTN) {
  const int b = blockIdx.y;
  const int h = blockIdx.z;
  const int i0 = (((h >> 2) & 1) ? (15 - (int)blockIdx.x) : (int)blockIdx.x) * 64;
  const int t = threadIdx.x;
  const int w = t >> 6;          // wave 0..3
  const int lane = t & 63;
  const int lq = lane & 15;
  const int lg = lane >> 4;

  __shared__ __align__(16) unsigned short Ks[4096];  // K tile  [j][d] bf16 swz
  __shared__ __align__(16) unsigned short Rs[4096];  // R tile  [jr][d] bf16 swz
  __shared__ __align__(16) unsigned short Vt[4096];  // V^T tile [d][j] bf16 swz
  __shared__ __align__(16) unsigned short Es[4096];  // P tile  [i][j] bf16 swz (Q stage at prologue)
  __shared__ __align__(16) float Ring[8192];         // BD+vr [i][128] f32 swz
  __shared__ float uks[64];

  // ---- prologue: stage Q (into Es space) + R window jr0p ----
  {
    const int jr0p = 960 - i0;   // in [0,960]
    #pragma unroll
    for (int it = 0; it < 4; ++it) {
      const int idx = it * 256 + t;
      const int row = idx >> 4, c4 = (idx & 15) * 4;
      const float4 q4 = *(const float4*)(QKV + ((size_t)(MEML + i0 + row) * 4 + b) * 1536 + h * 64 + c4);
      uint2 qp; CVT2(qp.x, q4.x, q4.y); CVT2(qp.y, q4.z, q4.w);
      *(uint2*)((char*)Es + SWZB(row, c4 * 2)) = qp;
      const float4 r4 = *(const float4*)(RK + (size_t)(jr0p + row) * 512 + h * 64 + c4);
      uint2 rp; CVT2(rp.x, r4.x, r4.y); CVT2(rp.y, r4.z, r4.w);
      *(uint2*)((char*)Rs + SWZB(row, c4 * 2)) = rp;
    }
  }
  __syncthreads();

  // ---- prefetch regs + loader ----
  float4 pk[4], pr[4], pvv[4];
  float puk;
  auto load_tile = [&](int n) {
    const int j0 = n * 64;
    const int jr0 = j0 - i0 + 1024;
    #pragma unroll
    for (int it = 0; it < 4; ++it) {
      const int idx = it * 256 + t;
      const int row = idx >> 4, c4 = (idx & 15) * 4;
      pk[it] = *(const float4*)(QKV + ((size_t)(j0 + row) * 4 + b) * 1536 + 512 + h * 64 + c4);
      const int jr = jr0 + row;
      float4 r4 = make_float4(0.f, 0.f, 0.f, 0.f);
      if (jr < 2048) r4 = *(const float4*)(RK + (size_t)jr * 512 + h * 64 + c4);
      pr[it] = r4;
    }
    const int jb = (t >> 4) * 4, db = (t & 15) * 4;
    const float* vb = QKV + ((size_t)(j0 + jb) * 4 + b) * 1536 + 1024 + h * 64 + db;
    pvv[0] = *(const float4*)(vb);
    pvv[1] = *(const float4*)(vb + 6144);
    pvv[2] = *(const float4*)(vb + 12288);
    pvv[3] = *(const float4*)(vb + 18432);
    puk = (t < 64) ? UK[(size_t)(b * 8 + h) * 2048 + j0 + t] : 0.f;
  };
  load_tile(0);   // in flight during prologue BD

  // ---- Q fragments to registers (rows w*16..w*16+15) ----
  const bf16x8 qf0 = *(const bf16x8*)((const char*)Es + SWZB(w * 16 + lq, lg * 16));
  const bf16x8 qf1 = *(const bf16x8*)((const char*)Es + SWZB(w * 16 + lq, 64 + lg * 16));

  // ---- prologue BD -> ring half at cols 64..127 ----
  {
    f32x4 zero = {0.f, 0.f, 0.f, 0.f};
    f32x4 bd[4];
    #pragma unroll
    for (int nj = 0; nj < 4; ++nj) bd[nj] = zero;
    #pragma unroll
    for (int nj = 0; nj < 4; ++nj) {
      const bf16x8 rf0 = *(const bf16x8*)((const char*)Rs + SWZB(nj * 16 + lq, lg * 16));
      const bf16x8 rf1 = *(const bf16x8*)((const char*)Rs + SWZB(nj * 16 + lq, 64 + lg * 16));
      bd[nj] = MFMA16(qf0, rf0, bd[nj]);
      bd[nj] = MFMA16(qf1, rf1, bd[nj]);
    }
    const int jr0p = 960 - i0;
    #pragma unroll
    for (int nj = 0; nj < 4; ++nj) {
      const int jrl = nj * 16 + lq;
      const float vrv = VR[h * 2048 + jr0p + jrl];
      #pragma unroll
      for (int rg = 0; rg < 4; ++rg) {
        const int il = w * 16 + lg * 4 + rg;
        *(float*)((char*)Ring + RINGB(il, 64 + jrl)) = bd[nj][rg] + vrv;
      }
    }
  }

  f32x4 pv[4];
  {
    f32x4 zero = {0.f, 0.f, 0.f, 0.f};
    #pragma unroll
    for (int nd = 0; nd < 4; ++nd) pv[nd] = zero;
  }
  float rs[4] = {0.f, 0.f, 0.f, 0.f};

  const int ntiles = i0 / 64 + 17;
  for (int n = 0; n < ntiles; ++n) {
    const int j0 = n * 64;
    const int jr0 = j0 - i0 + 1024;
    __syncthreads();   // A: prefetch arrived; LDS tiles reusable
    // ---- stage K + R from prefetch regs ----
    #pragma unroll
    for (int it = 0; it < 4; ++it) {
      const int idx = it * 256 + t;
      const int row = idx >> 4, c4 = (idx & 15) * 4;
      uint2 kp; CVT2(kp.x, pk[it].x, pk[it].y); CVT2(kp.y, pk[it].z, pk[it].w);
      *(uint2*)((char*)Ks + SWZB(row, c4 * 2)) = kp;
      uint2 rp; CVT2(rp.x, pr[it].x, pr[it].y); CVT2(rp.y, pr[it].z, pr[it].w);
      *(uint2*)((char*)Rs + SWZB(row, c4 * 2)) = rp;
    }
    // ---- stage V transposed from prefetch regs ----
    {
      const int jb = (t >> 4) * 4, db = (t & 15) * 4;
      uint2 wv;
      CVT2(wv.x, pvv[0].x, pvv[1].x); CVT2(wv.y, pvv[2].x, pvv[3].x);
      *(uint2*)((char*)Vt + SWZB(db + 0, jb * 2)) = wv;
      CVT2(wv.x, pvv[0].y, pvv[1].y); CVT2(wv.y, pvv[2].y, pvv[3].y);
      *(uint2*)((char*)Vt + SWZB(db + 1, jb * 2)) = wv;
      CVT2(wv.x, pvv[0].z, pvv[1].z); CVT2(wv.y, pvv[2].z, pvv[3].z);
      *(uint2*)((char*)Vt + SWZB(db + 2, jb * 2)) = wv;
      CVT2(wv.x, pvv[0].w, pvv[1].w); CVT2(wv.y, pvv[2].w, pvv[3].w);
      *(uint2*)((char*)Vt + SWZB(db + 3, jb * 2)) = wv;
    }
    if (t < 64) uks[t] = puk;
    __syncthreads();   // B: LDS ready
    if (n + 1 < ntiles) load_tile(n + 1);   // prefetch during compute
    // ---- AC and BD MFMAs ----
    f32x4 acc[4], bdn[4];
    {
      f32x4 zero = {0.f, 0.f, 0.f, 0.f};
      #pragma unroll
      for (int nj = 0; nj < 4; ++nj) { acc[nj] = zero; bdn[nj] = zero; }
    }
    #pragma unroll
    for (int nj = 0; nj < 4; ++nj) {
      const bf16x8 kf0 = *(const bf16x8*)((const char*)Ks + SWZB(nj * 16 + lq, lg * 16));
      const bf16x8 rf0 = *(const bf16x8*)((const char*)Rs + SWZB(nj * 16 + lq, lg * 16));
      acc[nj] = MFMA16(qf0, kf0, acc[nj]);
      bdn[nj] = MFMA16(qf0, rf0, bdn[nj]);
      const bf16x8 kf1 = *(const bf16x8*)((const char*)Ks + SWZB(nj * 16 + lq, 64 + lg * 16));
      const bf16x8 rf1 = *(const bf16x8*)((const char*)Rs + SWZB(nj * 16 + lq, 64 + lg * 16));
      acc[nj] = MFMA16(qf1, kf1, acc[nj]);
      bdn[nj] = MFMA16(qf1, rf1, bdn[nj]);
    }
    const int base_cur = (n & 1) * 64;
    const int base_prev = 64 - base_cur;
    // ---- ring write (cur half), intra-wave only ----
    #pragma unroll
    for (int nj = 0; nj < 4; ++nj) {
      const int jrl = nj * 16 + lq;
      const int jrg = jr0 + jrl;
      const float vrv = (jrg < 2048) ? VR[h * 2048 + jrg] : 0.f;
      #pragma unroll
      for (int rg = 0; rg < 4; ++rg) {
        const int il = w * 16 + lg * 4 + rg;
        *(float*)((char*)Ring + RINGB(il, base_cur + jrl)) = bdn[nj][rg] + vrv;
      }
    }
    // ---- assemble scores, exp, write P tile (bf16) to Es (own rows) ----
    #pragma unroll
    for (int njp = 0; njp < 2; ++njp) {
      #pragma unroll
      for (int rg = 0; rg < 4; ++rg) {
        const int il = w * 16 + lg * 4 + rg;
        const int ig = i0 + il;
        float ee[2];
        #pragma unroll
        for (int q2 = 0; q2 < 2; ++q2) {
          const int nj = njp * 2 + q2;
          const int jl = nj * 16 + lq;
          const int jr_rel = jl - il + 63;
          const float ringv = (jr_rel < 64)
              ? *(const float*)((const char*)Ring + RINGB(il, base_prev + jr_rel))
              : *(const float*)((const char*)Ring + RINGB(il, base_cur + jr_rel - 64));
          const float s = 0.125f * (acc[nj][rg] + ringv + uks[jl]);
          const float e = (j0 + jl > ig + MEML) ? 0.f : __expf(s);
          rs[rg] += e;
          ee[q2] = e;
        }
        unsigned int pk2; CVT2(pk2, ee[0], ee[1]);
        const int jlA = (njp * 2) * 16 + lq;
        *(unsigned short*)((char*)Es + SWZB(il, jlA * 2)) = (unsigned short)(pk2 & 0xffffu);
        *(unsigned short*)((char*)Es + SWZB(il, (jlA + 16) * 2)) = (unsigned short)(pk2 >> 16);
      }
    }
    // ---- PV MFMAs (reads own-wave Es rows + Vt) ----
    {
      const bf16x8 pf0 = *(const bf16x8*)((const char*)Es + SWZB(w * 16 + lq, lg * 16));
      const bf16x8 pf1 = *(const bf16x8*)((const char*)Es + SWZB(w * 16 + lq, 64 + lg * 16));
      #pragma unroll
      for (int nd = 0; nd < 4; ++nd) {
        const bf16x8 vf0 = *(const bf16x8*)((const char*)Vt + SWZB(nd * 16 + lq, lg * 16));
        const bf16x8 vf1 = *(const bf16x8*)((const char*)Vt + SWZB(nd * 16 + lq, 64 + lg * 16));
        pv[nd] = MFMA16(pf0, vf0, pv[nd]);
        pv[nd] = MFMA16(pf1, vf1, pv[nd]);
      }
    }
    __syncthreads();   // C: full Es tile written (cross-wave for P store)
    // ---- vectorized P store from Es ----
    #pragma unroll
    for (int it = 0; it < 2; ++it) {
      const int c = it * 256 + t;
      const int row = c >> 3, c16 = c & 7;
      const uint4 val = *(const uint4*)((const char*)Es + SWZB(row, c16 * 16));
      *(uint4*)(P + ((size_t)(b * 8 + h) * 1024 + i0 + row) * 2048 + j0 + c16 * 8) = val;
    }
  }

  // ---- row sums -> inv; write INV; scale PV; store ATTN ----
  #pragma unroll
  for (int rg = 0; rg < 4; ++rg) {
    #pragma unroll
    for (int m = 1; m < 16; m <<= 1) rs[rg] += __shfl_xor(rs[rg], m, 64);
  }
  float inv[4];
  #pragma unroll
  for (int rg = 0; rg < 4; ++rg) inv[rg] = 1.0f / rs[rg];
  if (lq == 0) {
    #pragma unroll
    for (int rg = 0; rg < 4; ++rg)
      INV[(size_t)(b * 8 + h) * 1024 + i0 + w * 16 + lg * 4 + rg] = inv[rg];
  }
  #pragma unroll
  for (int nd = 0; nd < 4; ++nd) {
    #pragma unroll
    for (int rg = 0; rg < 4; ++rg) {
      ATTN[((size_t)(i0 + w * 16 + lg * 4 + rg) * 4 + b) * 512 + h * 64 + nd * 16 + lq] =
          pv[nd][rg] * inv[rg];
    }
  }
}

// ---------------- normalize + transpose P[b,h,i,j](bf16) -> prob[i,j,b,h] --
__global__ __launch_bounds__(256)
void ptrans_kernel(const unsigned short* __restrict__ P, const float* __restrict__ INV,
                   float* __restrict__ prob) {
  const int i  = blockIdx.x;
  const int j0 = blockIdx.y * 64;
  const int t  = threadIdx.x;
  __shared__ float tile[32][65];
  __shared__ float invs[32];
  const bool valid = j0 <= (i & ~63) + MEML;
  if (t < 32) invs[t] = INV[(size_t)t * 1024 + i];
  if (valid) {
    const int bh = t >> 3, part = t & 7;
    const uint4 raw = *(const uint4*)(P + ((size_t)bh * 1024 + i) * 2048 + j0 + part * 8);
    const unsigned int w[4] = {raw.x, raw.y, raw.z, raw.w};
    #pragma unroll
    for (int k = 0; k < 4; ++k) {
      tile[bh][part*8 + 2*k]     = __uint_as_float(w[k] << 16);
      tile[bh][part*8 + 2*k + 1] = __uint_as_float(w[k] & 0xffff0000u);
    }
  }
  __syncthreads();
  #pragma unroll
  for (int it = 0; it < 8; ++it) {
    const int idx = it * 256 + t;
    const int jl = idx >> 5, bh = idx & 31;
    const float val = valid ? tile[bh][jl] * invs[bh] : 0.f;
    prob[((size_t)i * 2048 + j0 + jl) * 32 + bh] = val;
  }
}

// ---------------- Residual + LayerNorm ----------------
__global__ __launch_bounds__(256)
void ln_res_kernel(const float* __restrict__ xa, const float* __restrict__ xb,
                   const float* __restrict__ g, const float* __restrict__ bb,
                   float* __restrict__ y) {
  const int rrow = blockIdx.x;
  const int t = threadIdx.x;
  const size_t base = (size_t)rrow * DM;
  __shared__ float red[256];
  const float a0 = xa[base + t]       + xb[base + t];
  const float a1 = xa[base + t + 256] + xb[base + t + 256];
  red[t] = a0 + a1; __syncthreads();
  for (int s = 128; s > 0; s >>= 1) { if (t < s) red[t] += red[t+s]; __syncthreads(); }
  const float mu = red[0] * (1.0f/512.0f);
  __syncthreads();
  red[t] = a0*a0 + a1*a1; __syncthreads();
  for (int s = 128; s > 0; s >>= 1) { if (t < s) red[t] += red[t+s]; __syncthreads(); }
  const float var = red[0] * (1.0f/512.0f) - mu*mu;
  const float w = rsqrtf(var + 1e-5f);
  y[base + t]       = (a0 - mu) * w * g[t]       + bb[t];
  y[base + t + 256] = (a1 - mu) * w * g[t + 256] + bb[t + 256];
}

extern "C" void kernel_launch(void* const* d_in, const int* in_sizes, int n_in,
                              void* d_out, int out_size, void* d_ws, size_t ws_size,
                              hipStream_t stream) {
  const float* inputs = (const float*)d_in[0];
  const float* r      = (const float*)d_in[1];
  const float* u      = (const float*)d_in[2];
  const float* v      = (const float*)d_in[3];
  const float* mem    = (const float*)d_in[4];
  const float* Wqkv   = (const float*)d_in[6];
  const float* Wr     = (const float*)d_in[7];
  const float* Wo     = (const float*)d_in[8];
  const float* ln1g   = (const float*)d_in[9];
  const float* ln1b   = (const float*)d_in[10];
  const float* w1     = (const float*)d_in[11];
  const float* b1     = (const float*)d_in[12];
  const float* w2     = (const float*)d_in[13];
  const float* b2     = (const float*)d_in[14];
  const float* ln2g   = (const float*)d_in[15];
  const float* ln2b   = (const float*)d_in[16];

  float* out  = (float*)d_out;              // [1024,4,512]
  float* prob = out + (size_t)QL*BSZ*DM;    // [1024,2048,4,8]

  // Workspace (floats). P(bf16) = 33,554,432 float-slots; total ~214 MB.
  float* ws   = (float*)d_ws;
  unsigned short* P = (unsigned short*)ws;   // [4*8][1024][2048] bf16
  float* QKV  = ws + 33554432;               // 8192*1536
  float* RK   = QKV + 12582912;              // 2048*512
  float* ATTN = RK + 1048576;                // 4096*512
  float* AO   = ATTN + 2097152;              // 4096*512
  float* Y    = AO + 2097152;                // 4096*512
  float* UK   = Y + 2097152;                 // 65536
  float* VR   = UK + 65536;                  // 16384
  float* INV  = VR + 16384;                  // 32768
  float* HM   = ws;                          // alias P (dead after ptrans): 4096*2048
  float* Z    = ws + 8388608;                // inside P region

  // early hi/lo set: aliases P region [0, 6.29M floats) -- dead before attn2
  unsigned short* CAThi  = (unsigned short*)ws;           // 8192*512
  unsigned short* CATlo  = CAThi + 4194304;
  unsigned short* Rhi    = CATlo + 4194304;               // 2048*512
  unsigned short* Rlo    = Rhi + 1048576;
  unsigned short* Wqkvhi = Rlo + 1048576;                 // 1536*512
  unsigned short* Wqkvlo = Wqkvhi + 786432;
  unsigned short* Wrhi   = Wqkvlo + 786432;               // 512*512
  unsigned short* Wrlo   = Wrhi + 262144;
  // late hi/lo set: P region float-slot 10M.. (clear of HM [0,8.39M), Z [8.39M,9.44M))
  unsigned short* Wohi = (unsigned short*)(ws + 10485760);  // 512*512
  unsigned short* Wolo = Wohi + 262144;
  unsigned short* w1hi = Wolo + 262144;                   // 2048*512
  unsigned short* w1lo = w1hi + 1048576;
  unsigned short* w2hi = w1lo + 1048576;                  // 512*2048
  unsigned short* w2lo = w2hi + 1048576;

  const dim3 blk256(256);

  // ---- early precvt (CAT = [mem; inputs], r, Wqkv, Wr) ----
  precvt_kernel<<<dim3(2048), blk256, 0, stream>>>(mem, CAThi, CATlo, 524288);
  precvt_kernel<<<dim3(2048), blk256, 0, stream>>>(inputs, CAThi + 2097152, CATlo + 2097152, 524288);
  precvt_kernel<<<dim3(1024), blk256, 0, stream>>>(r, Rhi, Rlo, 262144);
  precvt_kernel<<<dim3(768),  blk256, 0, stream>>>(Wqkv, Wqkvhi, Wqkvlo, 196608);
  precvt_kernel<<<dim3(256),  blk256, 0, stream>>>(Wr, Wrhi, Wrlo, 65536);

  // QKV: [8192,1536] = cat(mem,inputs) @ Wqkv^T, K=512
  gemm_nt_mfma<128,true,false,false><<<dim3(12, 64), blk256, 0, stream>>>(
      nullptr, nullptr, 0, CAThi, CATlo, Wqkvhi, Wqkvlo, nullptr, QKV, 8192, 1536, 512);
  // RK: [2048,512] = r @ Wr^T, K=512
  gemm_nt_mfma<64,true,false,false><<<dim3(4, 32), blk256, 0, stream>>>(
      nullptr, nullptr, 0, Rhi, Rlo, Wrhi, Wrlo, nullptr, RK, 2048, 512, 512);
  ukvr_kernel<<<dim3(320), blk256, 0, stream>>>(QKV, RK, u, v, UK, VR);
  attn2_kernel<<<dim3(16, BSZ, NH), blk256, 0, stream>>>(QKV, RK, UK, VR, P, INV, ATTN);
  ptrans_kernel<<<dim3(1024, 32), blk256, 0, stream>>>(P, INV, prob);

  // ---- late precvt (P dead after ptrans) ----
  precvt_kernel<<<dim3(256),  blk256, 0, stream>>>(Wo, Wohi, Wolo, 65536);
  precvt_kernel<<<dim3(1024), blk256, 0, stream>>>(w1, w1hi, w1lo, 262144);
  precvt_kernel<<<dim3(1024), blk256, 0, stream>>>(w2, w2hi, w2lo, 262144);

  // AO: [4096,512] = ATTN @ Wo^T, K=512
  gemm_nt_mfma<64,false,false,false><<<dim3(4, 64), blk256, 0, stream>>>(
      ATTN, ATTN, 4096, nullptr, nullptr, Wohi, Wolo, nullptr, AO, 4096, 512, 512);
  ln_res_kernel<<<dim3(4096), blk256, 0, stream>>>(inputs, AO, ln1g, ln1b, Y);
  // HM: [4096,2048] = Y @ w1^T + b1, relu, K=512
  gemm_nt_mfma<128,false,true,true><<<dim3(16, 32), blk256, 0, stream>>>(
      Y, Y, 4096, nullptr, nullptr, w1hi, w1lo, b1, HM, 4096, 2048, 512);
  // Z: [4096,512] = HM @ w2^T + b2, K=2048
  gemm_nt_mfma<64,false,true,false><<<dim3(4, 64), blk256, 0, stream>>>(
      HM, HM, 4096, nullptr, nullptr, w2hi, w2lo, b2, Z, 4096, 512, 2048);
  ln_res_kernel<<<dim3(4096), blk256, 0, stream>>>(Y, Z, ln2g, ln2b, out);
}

// Round 4
// 643.586 us; speedup vs baseline: 2.9963x; 1.1214x over previous
//
#include <hip/hip_runtime.h>
#include <math.h>

#define QL 1024
#define BSZ 4
#define DM 512
#define NH 8
#define DHH 64
#define MEML 1024
#define KL 2048
#define DMLP 2048

typedef __attribute__((ext_vector_type(8))) short bf16x8;
typedef __attribute__((ext_vector_type(4))) float f32x4;

#define MFMA16(A, B, C) __builtin_amdgcn_mfma_f32_16x16x32_bf16((A), (B), (C), 0, 0, 0)
// byte offset into a [rows][64] bf16 tile (row stride 128B), T2 XOR-swizzled
#define SWZB(r, cb) (((r) << 7) + ((cb) ^ (((r) & 7) << 4)))
// byte offset into the [64][128] f32 ring (row stride 512B), same swizzle
#define RINGB(r, c) (((r) << 9) + ((((c) << 2)) ^ (((r) & 7) << 4)))
#define CVT2(dst, lo, hi) \
  asm("v_cvt_pk_bf16_f32 %0, %1, %2" : "=v"(dst) : "v"(lo), "v"(hi))
// async global->LDS, 16B per lane; LDS dest wave-uniform, global addr per-lane
#define GLOAD_LDS(gp, lp) __builtin_amdgcn_global_load_lds( \
    (const __attribute__((address_space(1))) void*)(gp), \
    (__attribute__((address_space(3))) void*)(lp), 16, 0, 0)

// ---------------- split fp32 -> (hi, lo) bf16 ------------------------------
__device__ __forceinline__ void split_bf16(const float4 a, uint2& h, uint2& l) {
  CVT2(h.x, a.x, a.y); CVT2(h.y, a.z, a.w);
  float4 r;
  r.x = a.x - __uint_as_float(h.x << 16);
  r.y = a.y - __uint_as_float(h.x & 0xffff0000u);
  r.z = a.z - __uint_as_float(h.y << 16);
  r.w = a.w - __uint_as_float(h.y & 0xffff0000u);
  CVT2(l.x, r.x, r.y); CVT2(l.y, r.z, r.w);
}

// store into pre-swizzled tiled layout [row/128][c0/64][128][64] (bf16)
__device__ __forceinline__ void store_tiled(char* hiB, char* loB, int KT,
                                            int row, int c0, uint2 h, uint2 l) {
  const size_t off = (((size_t)(row >> 7) * KT + (c0 >> 6)) << 14)
                   + SWZB(row & 127, (c0 & 63) * 2);
  *(uint2*)(hiB + off) = h;
  *(uint2*)(loB + off) = l;
}

// ---------------- fused precvt (early set) ---------------------------------
__global__ __launch_bounds__(256)
void precvt_early(const float* __restrict__ mem, const float* __restrict__ inputs,
                  const float* __restrict__ r, const float* __restrict__ Wqkv,
                  const float* __restrict__ Wr,
                  unsigned short* CAThi, unsigned short* CATlo,
                  unsigned short* Rhi, unsigned short* Rlo,
                  unsigned short* Qhi, unsigned short* Qlo,
                  unsigned short* WrHi, unsigned short* WrLo) {
  const int id = blockIdx.x * 256 + threadIdx.x;
  float4 a; uint2 h, l;
  if (id < 1048576) {            // CAT = [mem; inputs], 8192 x 512
    const int row = id >> 7, c0 = (id & 127) * 4;
    const float* s = (row < 4096) ? mem + (size_t)row * 512
                                  : inputs + (size_t)(row - 4096) * 512;
    a = *(const float4*)(s + c0);
    split_bf16(a, h, l);
    store_tiled((char*)CAThi, (char*)CATlo, 8, row, c0, h, l);
  } else if (id < 1310720) {     // r, 2048 x 512
    const int e = id - 1048576, row = e >> 7, c0 = (e & 127) * 4;
    a = *(const float4*)(r + (size_t)row * 512 + c0);
    split_bf16(a, h, l);
    store_tiled((char*)Rhi, (char*)Rlo, 8, row, c0, h, l);
  } else if (id < 1507328) {     // Wqkv, 1536 x 512
    const int e = id - 1310720, row = e >> 7, c0 = (e & 127) * 4;
    a = *(const float4*)(Wqkv + (size_t)row * 512 + c0);
    split_bf16(a, h, l);
    store_tiled((char*)Qhi, (char*)Qlo, 8, row, c0, h, l);
  } else if (id < 1572864) {     // Wr, 512 x 512
    const int e = id - 1507328, row = e >> 7, c0 = (e & 127) * 4;
    a = *(const float4*)(Wr + (size_t)row * 512 + c0);
    split_bf16(a, h, l);
    store_tiled((char*)WrHi, (char*)WrLo, 8, row, c0, h, l);
  }
}

// ---------------- fused precvt (late set) ----------------------------------
__global__ __launch_bounds__(256)
void precvt_late(const float* __restrict__ Wo, const float* __restrict__ w1,
                 const float* __restrict__ w2,
                 unsigned short* WoHi, unsigned short* WoLo,
                 unsigned short* w1Hi, unsigned short* w1Lo,
                 unsigned short* w2Hi, unsigned short* w2Lo) {
  const int id = blockIdx.x * 256 + threadIdx.x;
  float4 a; uint2 h, l;
  if (id < 65536) {              // Wo, 512 x 512
    const int row = id >> 7, c0 = (id & 127) * 4;
    a = *(const float4*)(Wo + (size_t)row * 512 + c0);
    split_bf16(a, h, l);
    store_tiled((char*)WoHi, (char*)WoLo, 8, row, c0, h, l);
  } else if (id < 327680) {      // w1, 2048 x 512
    const int e = id - 65536, row = e >> 7, c0 = (e & 127) * 4;
    a = *(const float4*)(w1 + (size_t)row * 512 + c0);
    split_bf16(a, h, l);
    store_tiled((char*)w1Hi, (char*)w1Lo, 8, row, c0, h, l);
  } else if (id < 589824) {      // w2, 512 x 2048
    const int e = id - 327680, row = e >> 9, c0 = (e & 511) * 4;
    a = *(const float4*)(w2 + (size_t)row * 2048 + c0);
    split_bf16(a, h, l);
    store_tiled((char*)w2Hi, (char*)w2Lo, 32, row, c0, h, l);
  }
}

// ---------------- MFMA GEMM: C[M,N] = A[M,K] @ W[N,K]^T (+bias, +relu) -----
// Split-bf16 fp32-quality (3 MFMAs / logical tile).
// W always via global_load_lds from pre-swizzled tiled hi/lo.
// A: AGLDS -> same path; else fp32 reg-prefetch + in-loop cvt.
template<int BM, bool AGLDS, bool BIAS, bool RELU>
__global__ __launch_bounds__(256)
void gemm_nt_mfma(const float* __restrict__ A0, const float* __restrict__ A1, int M0,
                  const unsigned short* __restrict__ AhiT, const unsigned short* __restrict__ AloT,
                  const unsigned short* __restrict__ WhiT, const unsigned short* __restrict__ WloT,
                  const float* __restrict__ bias,
                  float* __restrict__ C, int M, int N, int K) {
  constexpr int MR = 4;
  constexpr int NR = (BM == 128) ? 4 : 2;
  constexpr int AU = BM / 16;
  __shared__ __align__(16) unsigned short Ahi[BM * 64];
  __shared__ __align__(16) unsigned short Alo[BM * 64];
  __shared__ __align__(16) unsigned short Bhi[128 * 64];
  __shared__ __align__(16) unsigned short Blo[128 * 64];

  const int t = threadIdx.x;
  const int w = t >> 6, lane = t & 63;
  const int lq = lane & 15, lg = lane >> 4;
  const int row0 = blockIdx.y * BM, col0 = blockIdx.x * 128;
  const int wrow0 = (BM == 128) ? (w >> 1) * 64 : 0;
  const int wcol0 = (BM == 128) ? (w & 1) * 64 : w * 32;
  const int KT = K >> 6;
  const size_t amt = (size_t)(row0 >> 7) * KT;
  const int asub = (row0 & 127) << 7;     // byte offset into 128-row tile
  const size_t bnt = (size_t)(col0 >> 7) * KT;

  float4 paf[AU];
  auto loadA = [&](int k0) {
    if (!AGLDS) {
      #pragma unroll
      for (int it = 0; it < AU; ++it) {
        const int idx = it * 256 + t;
        const int row = idx >> 4, c4 = (idx & 15) * 4;
        const int grow = row0 + row;
        const float* src = (grow < M0) ? (A0 + (size_t)grow * K)
                                       : (A1 + (size_t)(grow - M0) * K);
        paf[it] = *(const float4*)(src + k0 + c4);
      }
    }
  };

  f32x4 acc[MR][NR];
  #pragma unroll
  for (int m = 0; m < MR; ++m)
    #pragma unroll
    for (int n = 0; n < NR; ++n)
      acc[m][n] = (f32x4){0.f, 0.f, 0.f, 0.f};

  loadA(0);
  for (int kt = 0; kt < KT; ++kt) {
    __syncthreads();   // prev MFMA done with LDS
    {  // W hi/lo via async global->LDS (pre-swizzled source, linear dest)
      const char* gbh = (const char*)WhiT + ((bnt + kt) << 14);
      const char* gbl = (const char*)WloT + ((bnt + kt) << 14);
      #pragma unroll
      for (int i = 0; i < 4; ++i) {
        const int off = (w * 4 + i) * 1024;
        GLOAD_LDS(gbh + off + lane * 16, (char*)Bhi + off);
        GLOAD_LDS(gbl + off + lane * 16, (char*)Blo + off);
      }
    }
    if (AGLDS) {
      const char* gah = (const char*)AhiT + ((amt + kt) << 14) + asub;
      const char* gal = (const char*)AloT + ((amt + kt) << 14) + asub;
      #pragma unroll
      for (int i = 0; i < BM / 32; ++i) {
        const int off = (w * (BM / 32) + i) * 1024;
        GLOAD_LDS(gah + off + lane * 16, (char*)Ahi + off);
        GLOAD_LDS(gal + off + lane * 16, (char*)Alo + off);
      }
    } else {
      #pragma unroll
      for (int it = 0; it < AU; ++it) {
        const int idx = it * 256 + t;
        const int row = idx >> 4, cb = (idx & 15) * 8;
        uint2 hi, lo;
        split_bf16(paf[it], hi, lo);
        *(uint2*)((char*)Ahi + SWZB(row, cb)) = hi;
        *(uint2*)((char*)Alo + SWZB(row, cb)) = lo;
      }
    }
    __syncthreads();   // vmcnt(0)+lgkm drain: all LDS ready
    if (!AGLDS && kt + 1 < KT) loadA((kt + 1) * 64);   // prefetch during MFMA
    #pragma unroll
    for (int ks = 0; ks < 2; ++ks) {
      bf16x8 ah[MR], al[MR], bh[NR], bl[NR];
      #pragma unroll
      for (int m = 0; m < MR; ++m) {
        ah[m] = *(const bf16x8*)((const char*)Ahi + SWZB(wrow0 + m * 16 + lq, ks * 64 + lg * 16));
        al[m] = *(const bf16x8*)((const char*)Alo + SWZB(wrow0 + m * 16 + lq, ks * 64 + lg * 16));
      }
      #pragma unroll
      for (int n = 0; n < NR; ++n) {
        bh[n] = *(const bf16x8*)((const char*)Bhi + SWZB(wcol0 + n * 16 + lq, ks * 64 + lg * 16));
        bl[n] = *(const bf16x8*)((const char*)Blo + SWZB(wcol0 + n * 16 + lq, ks * 64 + lg * 16));
      }
      #pragma unroll
      for (int m = 0; m < MR; ++m)
        #pragma unroll
        for (int n = 0; n < NR; ++n) {
          acc[m][n] = MFMA16(ah[m], bh[n], acc[m][n]);
          acc[m][n] = MFMA16(ah[m], bl[n], acc[m][n]);
          acc[m][n] = MFMA16(al[m], bh[n], acc[m][n]);
        }
    }
  }
  // ---- epilogue ----
  #pragma unroll
  for (int n = 0; n < NR; ++n) {
    const int col = col0 + wcol0 + n * 16 + lq;
    const float bv = BIAS ? bias[col] : 0.f;
    #pragma unroll
    for (int m = 0; m < MR; ++m) {
      #pragma unroll
      for (int rg = 0; rg < 4; ++rg) {
        const int row = row0 + wrow0 + m * 16 + lg * 4 + rg;
        float vv = acc[m][n][rg] + bv;
        if (RELU) vv = fmaxf(vv, 0.f);
        C[(size_t)row * N + col] = vv;
      }
    }
  }
}

// ---------------- MFMA attention ----------------
// Block = (64 q-rows, b, h); 4 waves, each wave owns 16 q-rows.
// u,v folded into Q operands: AC = (q+u)@K^T, BD = (q+v)@R^T.
// 2 barriers/tile: Ring/Es are strictly intra-wave (incl. per-wave P store).
__global__ __launch_bounds__(256)
void attn2_kernel(const float* __restrict__ QKV, const float* __restrict__ RK,
                  const float* __restrict__ u, const float* __restrict__ v,
                  unsigned short* __restrict__ P, float* __restrict__ INV,
                  float* __restrict__ ATTN) {
  const int b = blockIdx.y;
  const int h = blockIdx.z;
  const int i0 = (((h >> 2) & 1) ? (15 - (int)blockIdx.x) : (int)blockIdx.x) * 64;
  const int t = threadIdx.x;
  const int w = t >> 6;
  const int lane = t & 63;
  const int lq = lane & 15;
  const int lg = lane >> 4;

  __shared__ __align__(16) unsigned short Ks[4096];  // K tile [j][d] (Qv at prologue)
  __shared__ __align__(16) unsigned short Rs[4096];  // R tile [jr][d]
  __shared__ __align__(16) unsigned short Vt[4096];  // V^T tile [d][j]
  __shared__ __align__(16) unsigned short Es[4096];  // P tile [i][j] (Qu at prologue)
  __shared__ __align__(16) float Ring[8192];         // BD [i][128] f32 swz

  // ---- prologue: stage Qu -> Es, Qv -> Ks, R(jr0p) -> Rs ----
  {
    const int jr0p = 960 - i0;
    #pragma unroll
    for (int it = 0; it < 4; ++it) {
      const int idx = it * 256 + t;
      const int row = idx >> 4, c4 = (idx & 15) * 4;
      const float4 q4 = *(const float4*)(QKV + ((size_t)(MEML + i0 + row) * 4 + b) * 1536 + h * 64 + c4);
      const float4 u4 = *(const float4*)(u + h * 64 + c4);
      const float4 v4 = *(const float4*)(v + h * 64 + c4);
      uint2 qp;
      CVT2(qp.x, q4.x + u4.x, q4.y + u4.y); CVT2(qp.y, q4.z + u4.z, q4.w + u4.w);
      *(uint2*)((char*)Es + SWZB(row, c4 * 2)) = qp;
      CVT2(qp.x, q4.x + v4.x, q4.y + v4.y); CVT2(qp.y, q4.z + v4.z, q4.w + v4.w);
      *(uint2*)((char*)Ks + SWZB(row, c4 * 2)) = qp;
      const float4 r4 = *(const float4*)(RK + (size_t)(jr0p + row) * 512 + h * 64 + c4);
      CVT2(qp.x, r4.x, r4.y); CVT2(qp.y, r4.z, r4.w);
      *(uint2*)((char*)Rs + SWZB(row, c4 * 2)) = qp;
    }
  }
  __syncthreads();

  // ---- prefetch regs + loader ----
  float4 pk[4], pr[4], pvv[4];
  auto load_tile = [&](int n) {
    const int j0 = n * 64;
    const int jr0 = j0 - i0 + 1024;
    #pragma unroll
    for (int it = 0; it < 4; ++it) {
      const int idx = it * 256 + t;
      const int row = idx >> 4, c4 = (idx & 15) * 4;
      pk[it] = *(const float4*)(QKV + ((size_t)(j0 + row) * 4 + b) * 1536 + 512 + h * 64 + c4);
      const int jr = jr0 + row;
      float4 r4 = make_float4(0.f, 0.f, 0.f, 0.f);
      if (jr < 2048) r4 = *(const float4*)(RK + (size_t)jr * 512 + h * 64 + c4);
      pr[it] = r4;
    }
    const int jb = (t >> 4) * 4, db = (t & 15) * 4;
    const float* vb = QKV + ((size_t)(j0 + jb) * 4 + b) * 1536 + 1024 + h * 64 + db;
    pvv[0] = *(const float4*)(vb);
    pvv[1] = *(const float4*)(vb + 6144);
    pvv[2] = *(const float4*)(vb + 12288);
    pvv[3] = *(const float4*)(vb + 18432);
  };
  load_tile(0);   // in flight during prologue BD

  // ---- Q fragments (own 16 rows) ----
  const bf16x8 qu0 = *(const bf16x8*)((const char*)Es + SWZB(w * 16 + lq, lg * 16));
  const bf16x8 qu1 = *(const bf16x8*)((const char*)Es + SWZB(w * 16 + lq, 64 + lg * 16));
  const bf16x8 qv0 = *(const bf16x8*)((const char*)Ks + SWZB(w * 16 + lq, lg * 16));
  const bf16x8 qv1 = *(const bf16x8*)((const char*)Ks + SWZB(w * 16 + lq, 64 + lg * 16));

  // ---- prologue BD -> ring half at cols 64..127 ----
  {
    f32x4 bd[4];
    #pragma unroll
    for (int nj = 0; nj < 4; ++nj) bd[nj] = (f32x4){0.f, 0.f, 0.f, 0.f};
    #pragma unroll
    for (int nj = 0; nj < 4; ++nj) {
      const bf16x8 rf0 = *(const bf16x8*)((const char*)Rs + SWZB(nj * 16 + lq, lg * 16));
      const bf16x8 rf1 = *(const bf16x8*)((const char*)Rs + SWZB(nj * 16 + lq, 64 + lg * 16));
      bd[nj] = MFMA16(qv0, rf0, bd[nj]);
      bd[nj] = MFMA16(qv1, rf1, bd[nj]);
    }
    #pragma unroll
    for (int nj = 0; nj < 4; ++nj) {
      const int jrl = nj * 16 + lq;
      #pragma unroll
      for (int rg = 0; rg < 4; ++rg) {
        const int il = w * 16 + lg * 4 + rg;
        *(float*)((char*)Ring + RINGB(il, 64 + jrl)) = bd[nj][rg];
      }
    }
  }

  f32x4 pv[4];
  #pragma unroll
  for (int nd = 0; nd < 4; ++nd) pv[nd] = (f32x4){0.f, 0.f, 0.f, 0.f};
  float rs[4] = {0.f, 0.f, 0.f, 0.f};

  const int ntiles = i0 / 64 + 17;
  for (int n = 0; n < ntiles; ++n) {
    const int j0 = n * 64;
    __syncthreads();   // A: prefetch arrived; all waves done with LDS tiles
    // ---- stage K + R from prefetch regs ----
    #pragma unroll
    for (int it = 0; it < 4; ++it) {
      const int idx = it * 256 + t;
      const int row = idx >> 4, c4 = (idx & 15) * 4;
      uint2 kp; CVT2(kp.x, pk[it].x, pk[it].y); CVT2(kp.y, pk[it].z, pk[it].w);
      *(uint2*)((char*)Ks + SWZB(row, c4 * 2)) = kp;
      uint2 rp; CVT2(rp.x, pr[it].x, pr[it].y); CVT2(rp.y, pr[it].z, pr[it].w);
      *(uint2*)((char*)Rs + SWZB(row, c4 * 2)) = rp;
    }
    // ---- stage V transposed from prefetch regs ----
    {
      const int jb = (t >> 4) * 4, db = (t & 15) * 4;
      uint2 wv;
      CVT2(wv.x, pvv[0].x, pvv[1].x); CVT2(wv.y, pvv[2].x, pvv[3].x);
      *(uint2*)((char*)Vt + SWZB(db + 0, jb * 2)) = wv;
      CVT2(wv.x, pvv[0].y, pvv[1].y); CVT2(wv.y, pvv[2].y, pvv[3].y);
      *(uint2*)((char*)Vt + SWZB(db + 1, jb * 2)) = wv;
      CVT2(wv.x, pvv[0].z, pvv[1].z); CVT2(wv.y, pvv[2].z, pvv[3].z);
      *(uint2*)((char*)Vt + SWZB(db + 2, jb * 2)) = wv;
      CVT2(wv.x, pvv[0].w, pvv[1].w); CVT2(wv.y, pvv[2].w, pvv[3].w);
      *(uint2*)((char*)Vt + SWZB(db + 3, jb * 2)) = wv;
    }
    __syncthreads();   // B: LDS ready
    if (n + 1 < ntiles) load_tile(n + 1);   // prefetch during compute
    // ---- AC and BD MFMAs ----
    f32x4 acc[4], bdn[4];
    #pragma unroll
    for (int nj = 0; nj < 4; ++nj) {
      acc[nj] = (f32x4){0.f, 0.f, 0.f, 0.f};
      bdn[nj] = (f32x4){0.f, 0.f, 0.f, 0.f};
    }
    #pragma unroll
    for (int nj = 0; nj < 4; ++nj) {
      const bf16x8 kf0 = *(const bf16x8*)((const char*)Ks + SWZB(nj * 16 + lq, lg * 16));
      const bf16x8 rf0 = *(const bf16x8*)((const char*)Rs + SWZB(nj * 16 + lq, lg * 16));
      acc[nj] = MFMA16(qu0, kf0, acc[nj]);
      bdn[nj] = MFMA16(qv0, rf0, bdn[nj]);
      const bf16x8 kf1 = *(const bf16x8*)((const char*)Ks + SWZB(nj * 16 + lq, 64 + lg * 16));
      const bf16x8 rf1 = *(const bf16x8*)((const char*)Rs + SWZB(nj * 16 + lq, 64 + lg * 16));
      acc[nj] = MFMA16(qu1, kf1, acc[nj]);
      bdn[nj] = MFMA16(qv1, rf1, bdn[nj]);
    }
    const int base_cur = (n & 1) * 64;
    const int base_prev = 64 - base_cur;
    // ---- ring write (cur half), intra-wave ----
    #pragma unroll
    for (int nj = 0; nj < 4; ++nj) {
      const int jrl = nj * 16 + lq;
      #pragma unroll
      for (int rg = 0; rg < 4; ++rg) {
        const int il = w * 16 + lg * 4 + rg;
        *(float*)((char*)Ring + RINGB(il, base_cur + jrl)) = bdn[nj][rg];
      }
    }
    // ---- assemble scores, exp, write P tile (bf16) to Es (own rows) ----
    #pragma unroll
    for (int njp = 0; njp < 2; ++njp) {
      #pragma unroll
      for (int rg = 0; rg < 4; ++rg) {
        const int il = w * 16 + lg * 4 + rg;
        const int ig = i0 + il;
        float ee[2];
        #pragma unroll
        for (int q2 = 0; q2 < 2; ++q2) {
          const int nj = njp * 2 + q2;
          const int jl = nj * 16 + lq;
          const int jr_rel = jl - il + 63;
          const float ringv = (jr_rel < 64)
              ? *(const float*)((const char*)Ring + RINGB(il, base_prev + jr_rel))
              : *(const float*)((const char*)Ring + RINGB(il, base_cur + jr_rel - 64));
          const float s = 0.125f * (acc[nj][rg] + ringv);
          const float e = (j0 + jl > ig + MEML) ? 0.f : __expf(s);
          rs[rg] += e;
          ee[q2] = e;
        }
        unsigned int pk2; CVT2(pk2, ee[0], ee[1]);
        const int jlA = (njp * 2) * 16 + lq;
        *(unsigned short*)((char*)Es + SWZB(il, jlA * 2)) = (unsigned short)(pk2 & 0xffffu);
        *(unsigned short*)((char*)Es + SWZB(il, (jlA + 16) * 2)) = (unsigned short)(pk2 >> 16);
      }
    }
    // ---- PV MFMAs (own-wave Es rows + Vt) ----
    {
      const bf16x8 pf0 = *(const bf16x8*)((const char*)Es + SWZB(w * 16 + lq, lg * 16));
      const bf16x8 pf1 = *(const bf16x8*)((const char*)Es + SWZB(w * 16 + lq, 64 + lg * 16));
      #pragma unroll
      for (int nd = 0; nd < 4; ++nd) {
        const bf16x8 vf0 = *(const bf16x8*)((const char*)Vt + SWZB(nd * 16 + lq, lg * 16));
        const bf16x8 vf1 = *(const bf16x8*)((const char*)Vt + SWZB(nd * 16 + lq, 64 + lg * 16));
        pv[nd] = MFMA16(pf0, vf0, pv[nd]);
        pv[nd] = MFMA16(pf1, vf1, pv[nd]);
      }
    }
    // ---- per-wave P store (own 16 rows) -- no cross-wave barrier needed ----
    #pragma unroll
    for (int it = 0; it < 2; ++it) {
      const int lin = it * 64 + lane;
      const int rr = lin >> 3, c16 = lin & 7;
      const int row = w * 16 + rr;
      const uint4 val = *(const uint4*)((const char*)Es + SWZB(row, c16 * 16));
      *(uint4*)(P + ((size_t)(b * 8 + h) * 1024 + i0 + row) * 2048 + j0 + c16 * 8) = val;
    }
  }

  // ---- row sums -> inv; write INV; scale PV; store ATTN ----
  #pragma unroll
  for (int rg = 0; rg < 4; ++rg) {
    #pragma unroll
    for (int m = 1; m < 16; m <<= 1) rs[rg] += __shfl_xor(rs[rg], m, 64);
  }
  float inv[4];
  #pragma unroll
  for (int rg = 0; rg < 4; ++rg) inv[rg] = 1.0f / rs[rg];
  if (lq == 0) {
    #pragma unroll
    for (int rg = 0; rg < 4; ++rg)
      INV[(size_t)(b * 8 + h) * 1024 + i0 + w * 16 + lg * 4 + rg] = inv[rg];
  }
  #pragma unroll
  for (int nd = 0; nd < 4; ++nd) {
    #pragma unroll
    for (int rg = 0; rg < 4; ++rg) {
      ATTN[((size_t)(i0 + w * 16 + lg * 4 + rg) * 4 + b) * 512 + h * 64 + nd * 16 + lq] =
          pv[nd][rg] * inv[rg];
    }
  }
}

// ---------------- normalize + transpose P[b,h,i,j](bf16) -> prob[i,j,b,h] --
__global__ __launch_bounds__(256)
void ptrans_kernel(const unsigned short* __restrict__ P, const float* __restrict__ INV,
                   float* __restrict__ prob) {
  const int i  = blockIdx.x;
  const int j0 = blockIdx.y * 64;
  const int t  = threadIdx.x;
  __shared__ float tile[32][65];
  __shared__ float invs[32];
  const bool valid = j0 <= (i & ~63) + MEML;
  if (t < 32) invs[t] = INV[(size_t)t * 1024 + i];
  if (valid) {
    const int bh = t >> 3, part = t & 7;
    const uint4 raw = *(const uint4*)(P + ((size_t)bh * 1024 + i) * 2048 + j0 + part * 8);
    const unsigned int w[4] = {raw.x, raw.y, raw.z, raw.w};
    #pragma unroll
    for (int k = 0; k < 4; ++k) {
      tile[bh][part*8 + 2*k]     = __uint_as_float(w[k] << 16);
      tile[bh][part*8 + 2*k + 1] = __uint_as_float(w[k] & 0xffff0000u);
    }
  }
  __syncthreads();
  #pragma unroll
  for (int it = 0; it < 8; ++it) {
    const int idx = it * 256 + t;
    const int jl = idx >> 5, bh = idx & 31;
    const float val = valid ? tile[bh][jl] * invs[bh] : 0.f;
    prob[((size_t)i * 2048 + j0 + jl) * 32 + bh] = val;
  }
}

// ---------------- Residual + LayerNorm ----------------
__global__ __launch_bounds__(256)
void ln_res_kernel(const float* __restrict__ xa, const float* __restrict__ xb,
                   const float* __restrict__ g, const float* __restrict__ bb,
                   float* __restrict__ y) {
  const int rrow = blockIdx.x;
  const int t = threadIdx.x;
  const size_t base = (size_t)rrow * DM;
  __shared__ float red[256];
  const float a0 = xa[base + t]       + xb[base + t];
  const float a1 = xa[base + t + 256] + xb[base + t + 256];
  red[t] = a0 + a1; __syncthreads();
  for (int s = 128; s > 0; s >>= 1) { if (t < s) red[t] += red[t+s]; __syncthreads(); }
  const float mu = red[0] * (1.0f/512.0f);
  __syncthreads();
  red[t] = a0*a0 + a1*a1; __syncthreads();
  for (int s = 128; s > 0; s >>= 1) { if (t < s) red[t] += red[t+s]; __syncthreads(); }
  const float var = red[0] * (1.0f/512.0f) - mu*mu;
  const float w = rsqrtf(var + 1e-5f);
  y[base + t]       = (a0 - mu) * w * g[t]       + bb[t];
  y[base + t + 256] = (a1 - mu) * w * g[t + 256] + bb[t + 256];
}

extern "C" void kernel_launch(void* const* d_in, const int* in_sizes, int n_in,
                              void* d_out, int out_size, void* d_ws, size_t ws_size,
                              hipStream_t stream) {
  const float* inputs = (const float*)d_in[0];
  const float* r      = (const float*)d_in[1];
  const float* u      = (const float*)d_in[2];
  const float* v      = (const float*)d_in[3];
  const float* mem    = (const float*)d_in[4];
  const float* Wqkv   = (const float*)d_in[6];
  const float* Wr     = (const float*)d_in[7];
  const float* Wo     = (const float*)d_in[8];
  const float* ln1g   = (const float*)d_in[9];
  const float* ln1b   = (const float*)d_in[10];
  const float* w1     = (const float*)d_in[11];
  const float* b1     = (const float*)d_in[12];
  const float* w2     = (const float*)d_in[13];
  const float* b2     = (const float*)d_in[14];
  const float* ln2g   = (const float*)d_in[15];
  const float* ln2b   = (const float*)d_in[16];

  float* out  = (float*)d_out;              // [1024,4,512]
  float* prob = out + (size_t)QL*BSZ*DM;    // [1024,2048,4,8]

  // Workspace (float slots)
  float* ws   = (float*)d_ws;
  unsigned short* P = (unsigned short*)ws;   // [32][1024][2048] bf16 = 33,554,432 fl
  float* QKV  = ws + 33554432;               // 8192*1536
  float* RK   = QKV + 12582912;              // 2048*512
  float* ATTN = RK + 1048576;                // 4096*512
  float* AO   = ATTN + 2097152;              // 4096*512
  float* Y    = AO + 2097152;                // 4096*512
  float* INV  = Y + 2097152;                 // 32768
  float* HM   = ws;                          // alias P (dead after ptrans)
  float* Z    = ws + 8388608;                // inside P region

  // early tiled hi/lo (alias P region; dead before attn2 writes P)
  unsigned short* CAThiT = (unsigned short*)ws;            // 8192x512
  unsigned short* CATloT = CAThiT + 4194304;
  unsigned short* RhiT   = CATloT + 4194304;               // 2048x512
  unsigned short* RloT   = RhiT + 1048576;
  unsigned short* WqhiT  = RloT + 1048576;                 // 1536x512
  unsigned short* WqloT  = WqhiT + 786432;
  unsigned short* WrhiT  = WqloT + 786432;                 // 512x512
  unsigned short* WrloT  = WrhiT + 262144;
  // late tiled hi/lo (beyond all fp32 buffers; never aliased)
  unsigned short* WohiT = (unsigned short*)(ws + 53510144); // 512x512
  unsigned short* WoloT = WohiT + 262144;
  unsigned short* w1hiT = WoloT + 262144;                  // 2048x512
  unsigned short* w1loT = w1hiT + 1048576;
  unsigned short* w2hiT = w1loT + 1048576;                 // 512x2048
  unsigned short* w2loT = w2hiT + 1048576;

  const dim3 blk256(256);

  precvt_early<<<dim3(6144), blk256, 0, stream>>>(
      mem, inputs, r, Wqkv, Wr,
      CAThiT, CATloT, RhiT, RloT, WqhiT, WqloT, WrhiT, WrloT);
  precvt_late<<<dim3(2304), blk256, 0, stream>>>(
      Wo, w1, w2, WohiT, WoloT, w1hiT, w1loT, w2hiT, w2loT);

  // QKV: [8192,1536] = CAT @ Wqkv^T, K=512
  gemm_nt_mfma<128,true,false,false><<<dim3(12, 64), blk256, 0, stream>>>(
      nullptr, nullptr, 0, CAThiT, CATloT, WqhiT, WqloT, nullptr, QKV, 8192, 1536, 512);
  // RK: [2048,512] = r @ Wr^T, K=512
  gemm_nt_mfma<64,true,false,false><<<dim3(4, 32), blk256, 0, stream>>>(
      nullptr, nullptr, 0, RhiT, RloT, WrhiT, WrloT, nullptr, RK, 2048, 512, 512);
  attn2_kernel<<<dim3(16, BSZ, NH), blk256, 0, stream>>>(QKV, RK, u, v, P, INV, ATTN);
  ptrans_kernel<<<dim3(1024, 32), blk256, 0, stream>>>(P, INV, prob);

  // AO: [4096,512] = ATTN @ Wo^T, K=512
  gemm_nt_mfma<64,false,false,false><<<dim3(4, 64), blk256, 0, stream>>>(
      ATTN, ATTN, 4096, nullptr, nullptr, WohiT, WoloT, nullptr, AO, 4096, 512, 512);
  ln_res_kernel<<<dim3(4096), blk256, 0, stream>>>(inputs, AO, ln1g, ln1b, Y);
  // HM: [4096,2048] = Y @ w1^T + b1, relu, K=512
  gemm_nt_mfma<128,false,true,true><<<dim3(16, 32), blk256, 0, stream>>>(
      Y, Y, 4096, nullptr, nullptr, w1hiT, w1loT, b1, HM, 4096, 2048, 512);
  // Z: [4096,512] = HM @ w2^T + b2, K=2048
  gemm_nt_mfma<64,false,true,false><<<dim3(4, 64), blk256, 0, stream>>>(
      HM, HM, 4096, nullptr, nullptr, w2hiT, w2loT, b2, Z, 4096, 512, 2048);
  ln_res_kernel<<<dim3(4096), blk256, 0, stream>>>(Y, Z, ln2g, ln2b, out);
}